// Round 10
// baseline (283.080 us; speedup 1.0000x reference)
//
#include <hip/hip_runtime.h>
#include <hip/hip_bf16.h>

#define BB 2
#define TT 2048
#define CC 1024
#define HH 16
#define DH 64

typedef __attribute__((ext_vector_type(8))) short bf16x8;
typedef __attribute__((ext_vector_type(4))) float f32x4;
using bf16 = __hip_bfloat16;

union cvt8u { bf16x8 v; bf16 b[8]; };

__device__ __forceinline__ bf16x8 load8(const bf16* p) {
    return *reinterpret_cast<const bf16x8*>(p);
}

__device__ __forceinline__ bf16x8 cvt8f(const float* p) {
    const float4 a = *reinterpret_cast<const float4*>(p);
    const float4 c = *reinterpret_cast<const float4*>(p + 4);
    cvt8u u;
    u.b[0] = __float2bfloat16(a.x); u.b[1] = __float2bfloat16(a.y);
    u.b[2] = __float2bfloat16(a.z); u.b[3] = __float2bfloat16(a.w);
    u.b[4] = __float2bfloat16(c.x); u.b[5] = __float2bfloat16(c.y);
    u.b[6] = __float2bfloat16(c.z); u.b[7] = __float2bfloat16(c.w);
    return u.v;
}

__device__ __forceinline__ f32x4 mfma16(bf16x8 a, bf16x8 b, f32x4 c) {
    return __builtin_amdgcn_mfma_f32_16x16x32_bf16(a, b, c, 0, 0, 0);
}

// async global->LDS, 16 B per lane. HW rule: LDS dest = wave-uniform base +
// lane*16 (linear); the GLOBAL src is per-lane. (guide §5, m97/m104)
__device__ __forceinline__ void gload_lds16(const bf16* g, bf16* l) {
    __builtin_amdgcn_global_load_lds(
        (const __attribute__((address_space(1))) void*)g,
        (__attribute__((address_space(3))) void*)l, 16, 0, 0);
}

// Q pre-scale: 1/sqrt(64) * log2(e) so attention can use exp2 (v_exp_f32
// is a base-2 exp; this removes a v_mul per score from the softmax chain).
#define QSCALE (0.125f * 1.44269504088896f)

// V^T SKEWED LAYOUT: element (d, t) of a head's V^T is stored at
//   d*TT + ((t + d*64) & (TT-1))
// (round 9: perf-neutral vs linear, kept since proven correct — removes the
// 4 KB power-of-2 lane stride as a variable.)

// ---------------- fp32 -> bf16 staging kernels ------------------------------
__global__ __launch_bounds__(256) void cvt_x(const float* __restrict__ in,
                                             bf16* __restrict__ out) {
    const int i = blockIdx.x * 256 + threadIdx.x;  // 524288 groups of 8
    *(reinterpret_cast<bf16x8*>(out) + i) = cvt8f(in + (size_t)i * 8);
}

__global__ __launch_bounds__(256) void cvt4_w(const float* __restrict__ w0,
                                              const float* __restrict__ w1,
                                              const float* __restrict__ w2,
                                              const float* __restrict__ w3,
                                              bf16* __restrict__ out) {
    const float* in = (blockIdx.y == 0) ? w0 : (blockIdx.y == 1) ? w1
                    : (blockIdx.y == 2) ? w2 : w3;
    const int i = blockIdx.x * 256 + threadIdx.x;  // 131072 groups of 8 per matrix
    bf16* o = out + (size_t)blockIdx.y * CC * CC;
    *(reinterpret_cast<bf16x8*>(o) + i) = cvt8f(in + (size_t)i * 8);
}

// ---------------- LDS-staged GEMM (m97 structure) ---------------------------
// (structure unchanged from round 5 — proven. MODE-0 Vt epilogue skewed.)
template <int MODE>
__global__ __launch_bounds__(256) void gemm3(const bf16* __restrict__ A,
                                             const bf16* __restrict__ B,
                                             bf16* __restrict__ oq,
                                             bf16* __restrict__ ok,
                                             bf16* __restrict__ ov,
                                             float* __restrict__ outf) {
    __shared__ __align__(16) bf16 As[128 * 32];  // 8 KB, [row][k] row-major
    __shared__ __align__(16) bf16 Bs[128 * 32];  // 8 KB
    const int lane = threadIdx.x & 63;
    const int wv = threadIdx.x >> 6;
    const int l15 = lane & 15;
    const int g = lane >> 4;
    const int m0 = blockIdx.x * 128;
    const int n0 = blockIdx.y * 128;

    const int srow = wv * 16 + (lane >> 2);
    const int skg = (lane & 3) * 8;
    const bf16* gA0 = A + (size_t)(m0 + srow) * CC + skg;
    const bf16* gA1 = A + (size_t)(m0 + 64 + srow) * CC + skg;
    const bf16* gB0 = B + (size_t)(n0 + srow) * CC + skg;
    const bf16* gB1 = B + (size_t)(n0 + 64 + srow) * CC + skg;
    bf16* lA0 = As + wv * 512;          // wave-uniform LDS bases
    bf16* lA1 = As + 2048 + wv * 512;
    bf16* lB0 = Bs + wv * 512;
    bf16* lB1 = Bs + 2048 + wv * 512;

    const int mw = (wv >> 1) * 64;  // wave's 64x64 sub-tile
    const int nw = (wv & 1) * 64;

    f32x4 acc[4][4] = {};

    for (int kk = 0; kk < CC; kk += 32) {
        __syncthreads();  // previous tile's ds_reads done before overwrite
        gload_lds16(gA0 + kk, lA0);
        gload_lds16(gA1 + kk, lA1);
        gload_lds16(gB0 + kk, lB0);
        gload_lds16(gB1 + kk, lB1);
        __syncthreads();  // compiler drains vmcnt(0) before s_barrier -> tile ready

        bf16x8 af[4], wf[4];
#pragma unroll
        for (int mi = 0; mi < 4; mi++)
            af[mi] = load8(As + (mw + mi * 16 + l15) * 32 + g * 8);
#pragma unroll
        for (int ni = 0; ni < 4; ni++)
            wf[ni] = load8(Bs + (nw + ni * 16 + l15) * 32 + g * 8);
#pragma unroll
        for (int mi = 0; mi < 4; mi++)
#pragma unroll
            for (int ni = 0; ni < 4; ni++)
                acc[mi][ni] = mfma16(af[mi], wf[ni], acc[mi][ni]);
    }

#pragma unroll
    for (int mi = 0; mi < 4; mi++) {
#pragma unroll
        for (int ni = 0; ni < 4; ni++) {
            const int n = n0 + nw + ni * 16 + l15;  // C/D: col = lane&15
#pragma unroll
            for (int r = 0; r < 4; r++) {
                const int m = m0 + mw + mi * 16 + g * 4 + r;  // row=(lane>>4)*4+reg
                const float v = acc[mi][ni][r];
                if (MODE == 1) {
                    outf[(size_t)m * CC + n] = v;  // d_out is FLOAT32
                } else {
                    const int b = m >> 11, t = m & (TT - 1);
                    const int mat = n >> 10, nn = n & 1023;
                    const int h = nn >> 6, d = nn & 63;
                    if (mat == 0) {
                        oq[((size_t)((b * HH + h) * TT + t) << 6) + d] = __float2bfloat16(v * QSCALE);
                    } else if (mat == 1) {
                        ok[((size_t)((b * HH + h) * TT + t) << 6) + d] = __float2bfloat16(v);
                    } else {
                        // skewed V^T store (see layout comment above)
                        ov[(size_t)((b * HH + h) * DH + d) * TT + ((t + (d << 6)) & (TT - 1))] = __float2bfloat16(v);
                    }
                }
            }
        }
    }
}

// ---------------- register-direct GEMM (fallback, fp32 weights) -------------
template <int MODE>
__global__ __launch_bounds__(256) void gemm2(const bf16* __restrict__ A,
                                             const float* __restrict__ W0,
                                             const float* __restrict__ W1,
                                             const float* __restrict__ W2,
                                             bf16* __restrict__ oq,
                                             bf16* __restrict__ ok,
                                             bf16* __restrict__ ov,
                                             float* __restrict__ outf) {
    const int lane = threadIdx.x & 63;
    const int wv = threadIdx.x >> 6;
    const int l15 = lane & 15;
    const int g = lane >> 4;
    const int mw = blockIdx.x * 128 + (wv >> 1) * 64;
    const int nw = blockIdx.y * 128 + (wv & 1) * 64;

    f32x4 acc[4][4] = {};

    const bf16* ap[4];
#pragma unroll
    for (int mi = 0; mi < 4; mi++)
        ap[mi] = A + (size_t)(mw + mi * 16 + l15) * CC + g * 8;

    const float* wfp[4];
#pragma unroll
    for (int ni = 0; ni < 4; ni++) {
        const int nt = nw + ni * 16;
        const float* base = (MODE == 1) ? W0
                          : (nt < 1024) ? W0 : (nt < 2048) ? W1 : W2;
        wfp[ni] = base + (size_t)((nt & 1023) + l15) * CC + g * 8;
    }

#pragma unroll 2
    for (int kk = 0; kk < CC; kk += 32) {
        bf16x8 af[4], wf[4];
#pragma unroll
        for (int mi = 0; mi < 4; mi++) af[mi] = load8(ap[mi] + kk);
#pragma unroll
        for (int ni = 0; ni < 4; ni++) wf[ni] = cvt8f(wfp[ni] + kk);
#pragma unroll
        for (int mi = 0; mi < 4; mi++)
#pragma unroll
            for (int ni = 0; ni < 4; ni++)
                acc[mi][ni] = mfma16(af[mi], wf[ni], acc[mi][ni]);
    }

#pragma unroll
    for (int mi = 0; mi < 4; mi++) {
#pragma unroll
        for (int ni = 0; ni < 4; ni++) {
            const int n = nw + ni * 16 + l15;
#pragma unroll
            for (int r = 0; r < 4; r++) {
                const int m = mw + mi * 16 + g * 4 + r;
                const float v = acc[mi][ni][r];
                if (MODE == 1) {
                    outf[(size_t)m * CC + n] = v;
                } else {
                    const int b = m >> 11, t = m & (TT - 1);
                    const int mat = n >> 10, nn = n & 1023;
                    const int h = nn >> 6, d = nn & 63;
                    if (mat == 0) {
                        oq[((size_t)((b * HH + h) * TT + t) << 6) + d] = __float2bfloat16(v * QSCALE);
                    } else if (mat == 1) {
                        ok[((size_t)((b * HH + h) * TT + t) << 6) + d] = __float2bfloat16(v);
                    } else {
                        ov[(size_t)((b * HH + h) * DH + d) * TT + ((t + (d << 6)) & (TT - 1))] = __float2bfloat16(v);
                    }
                }
            }
        }
    }
}

// ---------------- MFMA flash attention v11 ----------------------------------
// RESIDENCY THEORY (round 9 post-mortem): v5..v10 all ran at 2-3 waves/SIMD
// because the tile-PAIR-per-wave design holds ~170 total regs (104-108 arch
// reported by rocprof + ~64 AGPR accumulators, unified file on gfx950) ->
// floor(512/170) = 3 waves/SIMD. Every scheduling fix inside one wave was
// irrelevant: the machine lacked WAVES, not in-wave overlap.
// v11: ONE tile per block (2 waves split-K x2), per-wave state ~half:
//   q 8 + kf 16 + vf 16 + S 16(acc) + o 16(acc) + l 4 + addr ~= 110 total
// -> 4 waves/SIMD. Balance now via block oversubscription: 4096 variable-
// length blocks over 256 CUs, scheduler back-fills short blocks.
// Everything else (split-K parity, masks, LDS round-trip, skewed V, XCD
// grouping) is v7/v10 verbatim.
__global__ __launch_bounds__(128, 2) void attn_v11(const bf16* __restrict__ Q,
                                                   const bf16* __restrict__ K,
                                                   const bf16* __restrict__ Vt,
                                                   bf16* __restrict__ out) {
    __shared__ __align__(16) bf16 p_lds[2][16 * 72];   // 4608 B
    __shared__ __align__(16) float o_cmb[4][64][4];    // 4096 B
    __shared__ float l_cmb[16];                        // 64 B
    const int lane = threadIdx.x & 63;
    const int wv = threadIdx.x >> 6;  // 0..1 = split-K half
    const int l15 = lane & 15;
    const int g = lane >> 4;

    // bid -> (bh, c): all 128 c-tiles of one bh share bid%8 (same XCD under
    // round-robin dispatch) -> K+V (512 KB/head) stay L2-resident. Bijective
    // over [0,4096): xcd 0..7, 4 bh per XCD, 128 tiles per bh.
    const int bid = blockIdx.x;
    const int xcd = bid & 7;
    const int idx = bid >> 3;            // 0..511
    const int bh = xcd * 4 + (idx >> 7); // 0..31
    const int c = idx & 127;             // 0..127 = q-tile index

    const int qb = c * 16;           // tile rows [qb, qb+16)
    const int nkb = (c >> 2) + 1;    // 64-key blocks: 1..32

    const bf16* Qh = Q + (size_t)bh * TT * DH;
    const bf16* Kh = K + (size_t)bh * TT * DH;
    const bf16* Vh = Vt + (size_t)bh * DH * TT;

    const bf16x8 q0 = load8(Qh + (size_t)(qb + l15) * DH + g * 8);
    const bf16x8 q1 = load8(Qh + (size_t)(qb + l15) * DH + 32 + g * 8);

    f32x4 o[4] = {};
    float l[4] = {0.0f, 0.0f, 0.0f, 0.0f};

    bf16* const pl = p_lds[wv];

    // Prefetch K fragments for this wave's first k-block (k0 = wv*64; rows
    // <= 127 always exist, so the wv==1,nkb==1 no-iteration case is safe)
    bf16x8 kf0[4], kf1[4];
#pragma unroll
    for (int j = 0; j < 4; j++) {
        kf0[j] = load8(Kh + (size_t)(wv * 64 + j * 16 + l15) * DH + g * 8);
        kf1[j] = load8(Kh + (size_t)(wv * 64 + j * 16 + l15) * DH + 32 + g * 8);
    }

    for (int kb = wv; kb < nkb; kb += 2) {
        const int k0 = kb * 64;

        f32x4 S[4] = {};
#pragma unroll
        for (int j = 0; j < 4; j++) {
            S[j] = mfma16(q0, kf0[j], S[j]);
            S[j] = mfma16(q1, kf1[j], S[j]);
        }

        // V loads for THIS block (consumed after the LDS round-trip).
        // Skewed addresses: row d shifted by (d*64)&2047.
        bf16x8 vf0[4], vf1[4];
#pragma unroll
        for (int dt = 0; dt < 4; dt++) {
            const int d0 = dt * 16 + l15;
            const int sk = (d0 << 6);
            vf0[dt] = load8(Vh + (size_t)d0 * TT + ((k0 + g * 8 + sk) & (TT - 1)));
            vf1[dt] = load8(Vh + (size_t)d0 * TT + ((k0 + 32 + g * 8 + sk) & (TT - 1)));
        }

        // Prefetch this wave's NEXT k-block (wave-uniform; overlaps exp+LDS+PV)
        if (kb + 2 < nkb) {
            const int kn = k0 + 128;
#pragma unroll
            for (int j = 0; j < 4; j++) {
                kf0[j] = load8(Kh + (size_t)(kn + j * 16 + l15) * DH + g * 8);
                kf1[j] = load8(Kh + (size_t)(kn + j * 16 + l15) * DH + 32 + g * 8);
            }
        }

        // Causal mask (only the tile's last k-block needs it)
        if (kb == nkb - 1) {
#pragma unroll
            for (int j = 0; j < 4; j++)
#pragma unroll
                for (int r = 0; r < 4; r++)
                    if (k0 + j * 16 + l15 > qb + g * 4 + r) S[j][r] = -1e30f;
        }

        // Max-free softmax (scores bounded; Q pre-scaled by log2e): P = 2^S
#pragma unroll
        for (int r = 0; r < 4; r++)
#pragma unroll
            for (int j = 0; j < 4; j++) {
                S[j][r] = exp2f(S[j][r]);
                l[r] += S[j][r];
            }

        // C/D layout -> A-operand layout via per-wave LDS round-trip (bf16)
#pragma unroll
        for (int j = 0; j < 4; j++)
#pragma unroll
            for (int r = 0; r < 4; r++)
                pl[(g * 4 + r) * 72 + j * 16 + l15] = __float2bfloat16(S[j][r]);
        // DS-only RAW fence: wait LDS writes, do NOT drain vmcnt
        asm volatile("s_waitcnt lgkmcnt(0)" ::: "memory");

        const bf16x8 pf0 = load8(pl + l15 * 72 + g * 8);
        const bf16x8 pf1 = load8(pl + l15 * 72 + 32 + g * 8);
#pragma unroll
        for (int dt = 0; dt < 4; dt++) {
            o[dt] = mfma16(pf0, vf0[dt], o[dt]);
            o[dt] = mfma16(pf1, vf1[dt], o[dt]);
        }
    }

    // Per-wave row-sum reduce over the key-lane axis (l15: masks 1,2,4,8).
#pragma unroll
    for (int xm = 1; xm < 16; xm <<= 1) {
#pragma unroll
        for (int r = 0; r < 4; r++) l[r] += __shfl_xor(l[r], xm);
    }

    // Split-K combine: wave 1 publishes partials; wave 0 merges and writes.
    if (wv == 1) {
#pragma unroll
        for (int dt = 0; dt < 4; dt++)
            *reinterpret_cast<f32x4*>(&o_cmb[dt][lane][0]) = o[dt];
        if (l15 == 0) {
#pragma unroll
            for (int r = 0; r < 4; r++) l_cmb[g * 4 + r] = l[r];
        }
    }
    __syncthreads();
    if (wv == 1) return;

#pragma unroll
    for (int dt = 0; dt < 4; dt++)
        o[dt] += *reinterpret_cast<const f32x4*>(&o_cmb[dt][lane][0]);
#pragma unroll
    for (int r = 0; r < 4; r++) l[r] += l_cmb[g * 4 + r];

    const int b = bh >> 4, h = bh & 15;
#pragma unroll
    for (int r = 0; r < 4; r++) {
        const float inv = 1.0f / l[r];
        const int t = qb + g * 4 + r;
        bf16* op = out + (size_t)(b * TT + t) * CC + h * DH;
#pragma unroll
        for (int dt = 0; dt < 4; dt++)
            op[dt * 16 + l15] = __float2bfloat16(o[dt][r] * inv);
    }
}

extern "C" void kernel_launch(void* const* d_in, const int* in_sizes, int n_in,
                              void* d_out, int out_size, void* d_ws, size_t ws_size,
                              hipStream_t stream) {
    const float* x  = (const float*)d_in[0];
    const float* Wq = (const float*)d_in[1];
    const float* Wk = (const float*)d_in[2];
    const float* Wv = (const float*)d_in[3];
    const float* Wo = (const float*)d_in[4];
    float* out = (float*)d_out;  // reference output dtype is float32

    const size_t per = (size_t)BB * HH * TT * DH;  // 4,194,304 elems
    bf16* Qws  = (bf16*)d_ws;       // 8 MB
    bf16* Kws  = Qws + per;         // 8 MB
    bf16* Vtws = Kws + per;         // 8 MB (skewed layout, same footprint)
    bf16* xbf  = Vtws + per;        // 8 MB — attn output aliases (x dead after QKV)
    bf16* attn = xbf;
    bf16* Wball = attn + per;       // 8 MB (4 bf16 weight mats) — needs ws >= 40 MB
    const bool full = ws_size >= 5 * per * sizeof(bf16);

    const dim3 blk(256);
    cvt_x<<<dim3(2048), blk, 0, stream>>>(x, xbf);

    if (full) {
        cvt4_w<<<dim3(512, 4), blk, 0, stream>>>(Wq, Wk, Wv, Wo, Wball);
        gemm3<0><<<dim3(32, 24), blk, 0, stream>>>(
            xbf, Wball, Qws, Kws, Vtws, nullptr);
    } else {
        gemm2<0><<<dim3(32, 24), blk, 0, stream>>>(
            xbf, Wq, Wk, Wv, Qws, Kws, Vtws, nullptr);
    }

    attn_v11<<<dim3(4096), dim3(128), 0, stream>>>(Qws, Kws, Vtws, attn);

    if (full) {
        gemm3<1><<<dim3(32, 8), blk, 0, stream>>>(
            attn, Wball + (size_t)3 * CC * CC, nullptr, nullptr, nullptr, out);
    } else {
        gemm2<1><<<dim3(32, 8), blk, 0, stream>>>(
            attn, Wo, nullptr, nullptr, nullptr, nullptr, nullptr, out);
    }
}

// Round 11
// 248.725 us; speedup vs baseline: 1.1381x; 1.1381x over previous
//
#include <hip/hip_runtime.h>
#include <hip/hip_bf16.h>

#define BB 2
#define TT 2048
#define CC 1024
#define HH 16
#define DH 64

typedef __attribute__((ext_vector_type(8))) short bf16x8;
typedef __attribute__((ext_vector_type(4))) float f32x4;
using bf16 = __hip_bfloat16;

union cvt8u { bf16x8 v; bf16 b[8]; };

__device__ __forceinline__ bf16x8 load8(const bf16* p) {
    return *reinterpret_cast<const bf16x8*>(p);
}

__device__ __forceinline__ bf16x8 cvt8f(const float* p) {
    const float4 a = *reinterpret_cast<const float4*>(p);
    const float4 c = *reinterpret_cast<const float4*>(p + 4);
    cvt8u u;
    u.b[0] = __float2bfloat16(a.x); u.b[1] = __float2bfloat16(a.y);
    u.b[2] = __float2bfloat16(a.z); u.b[3] = __float2bfloat16(a.w);
    u.b[4] = __float2bfloat16(c.x); u.b[5] = __float2bfloat16(c.y);
    u.b[6] = __float2bfloat16(c.z); u.b[7] = __float2bfloat16(c.w);
    return u.v;
}

__device__ __forceinline__ f32x4 mfma16(bf16x8 a, bf16x8 b, f32x4 c) {
    return __builtin_amdgcn_mfma_f32_16x16x32_bf16(a, b, c, 0, 0, 0);
}

// async global->LDS, 16 B per lane. HW rule: LDS dest = wave-uniform base +
// lane*16 (linear); the GLOBAL src is per-lane. (guide §5, m97/m104)
__device__ __forceinline__ void gload_lds16(const bf16* g, bf16* l) {
    __builtin_amdgcn_global_load_lds(
        (const __attribute__((address_space(1))) void*)g,
        (__attribute__((address_space(3))) void*)l, 16, 0, 0);
}

// Q pre-scale: 1/sqrt(64) * log2(e) so attention can use exp2 (v_exp_f32
// is a base-2 exp; this removes a v_mul per score from the softmax chain).
#define QSCALE (0.125f * 1.44269504088896f)

// V^T SKEWED LAYOUT: element (d, t) of a head's V^T is stored at
//   d*TT + ((t + d*64) & (TT-1))
// (round 9: perf-neutral vs linear, kept since proven correct.)

// ---------------- fp32 -> bf16 staging kernels ------------------------------
__global__ __launch_bounds__(256) void cvt_x(const float* __restrict__ in,
                                             bf16* __restrict__ out) {
    const int i = blockIdx.x * 256 + threadIdx.x;  // 524288 groups of 8
    *(reinterpret_cast<bf16x8*>(out) + i) = cvt8f(in + (size_t)i * 8);
}

__global__ __launch_bounds__(256) void cvt4_w(const float* __restrict__ w0,
                                              const float* __restrict__ w1,
                                              const float* __restrict__ w2,
                                              const float* __restrict__ w3,
                                              bf16* __restrict__ out) {
    const float* in = (blockIdx.y == 0) ? w0 : (blockIdx.y == 1) ? w1
                    : (blockIdx.y == 2) ? w2 : w3;
    const int i = blockIdx.x * 256 + threadIdx.x;  // 131072 groups of 8 per matrix
    bf16* o = out + (size_t)blockIdx.y * CC * CC;
    *(reinterpret_cast<bf16x8*>(o) + i) = cvt8f(in + (size_t)i * 8);
}

// ---------------- LDS-staged GEMM (m97 structure) ---------------------------
// (structure unchanged from round 5 — proven. MODE-0 Vt epilogue skewed.)
template <int MODE>
__global__ __launch_bounds__(256) void gemm3(const bf16* __restrict__ A,
                                             const bf16* __restrict__ B,
                                             bf16* __restrict__ oq,
                                             bf16* __restrict__ ok,
                                             bf16* __restrict__ ov,
                                             float* __restrict__ outf) {
    __shared__ __align__(16) bf16 As[128 * 32];  // 8 KB, [row][k] row-major
    __shared__ __align__(16) bf16 Bs[128 * 32];  // 8 KB
    const int lane = threadIdx.x & 63;
    const int wv = threadIdx.x >> 6;
    const int l15 = lane & 15;
    const int g = lane >> 4;
    const int m0 = blockIdx.x * 128;
    const int n0 = blockIdx.y * 128;

    const int srow = wv * 16 + (lane >> 2);
    const int skg = (lane & 3) * 8;
    const bf16* gA0 = A + (size_t)(m0 + srow) * CC + skg;
    const bf16* gA1 = A + (size_t)(m0 + 64 + srow) * CC + skg;
    const bf16* gB0 = B + (size_t)(n0 + srow) * CC + skg;
    const bf16* gB1 = B + (size_t)(n0 + 64 + srow) * CC + skg;
    bf16* lA0 = As + wv * 512;          // wave-uniform LDS bases
    bf16* lA1 = As + 2048 + wv * 512;
    bf16* lB0 = Bs + wv * 512;
    bf16* lB1 = Bs + 2048 + wv * 512;

    const int mw = (wv >> 1) * 64;  // wave's 64x64 sub-tile
    const int nw = (wv & 1) * 64;

    f32x4 acc[4][4] = {};

    for (int kk = 0; kk < CC; kk += 32) {
        __syncthreads();  // previous tile's ds_reads done before overwrite
        gload_lds16(gA0 + kk, lA0);
        gload_lds16(gA1 + kk, lA1);
        gload_lds16(gB0 + kk, lB0);
        gload_lds16(gB1 + kk, lB1);
        __syncthreads();  // compiler drains vmcnt(0) before s_barrier -> tile ready

        bf16x8 af[4], wf[4];
#pragma unroll
        for (int mi = 0; mi < 4; mi++)
            af[mi] = load8(As + (mw + mi * 16 + l15) * 32 + g * 8);
#pragma unroll
        for (int ni = 0; ni < 4; ni++)
            wf[ni] = load8(Bs + (nw + ni * 16 + l15) * 32 + g * 8);
#pragma unroll
        for (int mi = 0; mi < 4; mi++)
#pragma unroll
            for (int ni = 0; ni < 4; ni++)
                acc[mi][ni] = mfma16(af[mi], wf[ni], acc[mi][ni]);
    }

#pragma unroll
    for (int mi = 0; mi < 4; mi++) {
#pragma unroll
        for (int ni = 0; ni < 4; ni++) {
            const int n = n0 + nw + ni * 16 + l15;  // C/D: col = lane&15
#pragma unroll
            for (int r = 0; r < 4; r++) {
                const int m = m0 + mw + mi * 16 + g * 4 + r;  // row=(lane>>4)*4+reg
                const float v = acc[mi][ni][r];
                if (MODE == 1) {
                    outf[(size_t)m * CC + n] = v;  // d_out is FLOAT32
                } else {
                    const int b = m >> 11, t = m & (TT - 1);
                    const int mat = n >> 10, nn = n & 1023;
                    const int h = nn >> 6, d = nn & 63;
                    if (mat == 0) {
                        oq[((size_t)((b * HH + h) * TT + t) << 6) + d] = __float2bfloat16(v * QSCALE);
                    } else if (mat == 1) {
                        ok[((size_t)((b * HH + h) * TT + t) << 6) + d] = __float2bfloat16(v);
                    } else {
                        // skewed V^T store (see layout comment above)
                        ov[(size_t)((b * HH + h) * DH + d) * TT + ((t + (d << 6)) & (TT - 1))] = __float2bfloat16(v);
                    }
                }
            }
        }
    }
}

// ---------------- register-direct GEMM (fallback, fp32 weights) -------------
template <int MODE>
__global__ __launch_bounds__(256) void gemm2(const bf16* __restrict__ A,
                                             const float* __restrict__ W0,
                                             const float* __restrict__ W1,
                                             const float* __restrict__ W2,
                                             bf16* __restrict__ oq,
                                             bf16* __restrict__ ok,
                                             bf16* __restrict__ ov,
                                             float* __restrict__ outf) {
    const int lane = threadIdx.x & 63;
    const int wv = threadIdx.x >> 6;
    const int l15 = lane & 15;
    const int g = lane >> 4;
    const int mw = blockIdx.x * 128 + (wv >> 1) * 64;
    const int nw = blockIdx.y * 128 + (wv & 1) * 64;

    f32x4 acc[4][4] = {};

    const bf16* ap[4];
#pragma unroll
    for (int mi = 0; mi < 4; mi++)
        ap[mi] = A + (size_t)(mw + mi * 16 + l15) * CC + g * 8;

    const float* wfp[4];
#pragma unroll
    for (int ni = 0; ni < 4; ni++) {
        const int nt = nw + ni * 16;
        const float* base = (MODE == 1) ? W0
                          : (nt < 1024) ? W0 : (nt < 2048) ? W1 : W2;
        wfp[ni] = base + (size_t)((nt & 1023) + l15) * CC + g * 8;
    }

#pragma unroll 2
    for (int kk = 0; kk < CC; kk += 32) {
        bf16x8 af[4], wf[4];
#pragma unroll
        for (int mi = 0; mi < 4; mi++) af[mi] = load8(ap[mi] + kk);
#pragma unroll
        for (int ni = 0; ni < 4; ni++) wf[ni] = cvt8f(wfp[ni] + kk);
#pragma unroll
        for (int mi = 0; mi < 4; mi++)
#pragma unroll
            for (int ni = 0; ni < 4; ni++)
                acc[mi][ni] = mfma16(af[mi], wf[ni], acc[mi][ni]);
    }

#pragma unroll
    for (int mi = 0; mi < 4; mi++) {
#pragma unroll
        for (int ni = 0; ni < 4; ni++) {
            const int n = nw + ni * 16 + l15;
#pragma unroll
            for (int r = 0; r < 4; r++) {
                const int m = mw + mi * 16 + g * 4 + r;
                const float v = acc[mi][ni][r];
                if (MODE == 1) {
                    outf[(size_t)m * CC + n] = v;
                } else {
                    const int b = m >> 11, t = m & (TT - 1);
                    const int mat = n >> 10, nn = n & 1023;
                    const int h = nn >> 6, d = nn & 63;
                    if (mat == 0) {
                        oq[((size_t)((b * HH + h) * TT + t) << 6) + d] = __float2bfloat16(v * QSCALE);
                    } else if (mat == 1) {
                        ok[((size_t)((b * HH + h) * TT + t) << 6) + d] = __float2bfloat16(v);
                    } else {
                        ov[(size_t)((b * HH + h) * DH + d) * TT + ((t + (d << 6)) & (TT - 1))] = __float2bfloat16(v);
                    }
                }
            }
        }
    }
}

// ---------------- MFMA flash attention v12 ----------------------------------
// Measured cost model (v7/v11 fit): time = 750 cyc fixed per iteration +
// ~600 per tile-unit. v11 (thin, 2x iters) regressed to 149us; v9 (fat in K)
// spilled (K-fatness doubles kf+vf regs). v12 goes FAT IN Q: one block owns
// q-tile QUAD {4cq..4cq+3} — all four have IDENTICAL trip count nkb = cq+1,
// so every tile is active every iteration (v7's pair wasted ~half its fat on
// the short tile). Per iteration: 64 MFMA sharing ONE set of K/V fragments
// (Q-fatness costs only accumulators: ~210 total regs -> 2 waves/SIMD, same
// as v7). Iterations: 16,896 vs v7's 33,792. Blocks dispatched longest-first
// (cq = 31-idx) to kill the tail. Split-K x2 and all verified pieces kept.
__global__ __launch_bounds__(128, 2) void attn_v12(const bf16* __restrict__ Q,
                                                   const bf16* __restrict__ K,
                                                   const bf16* __restrict__ Vt,
                                                   bf16* __restrict__ out) {
    // union: [0,18432) p_lds [2 wv][4 tile][1152 bf16]
    //        after loop: [0,16384) o_cmb [4 tile][4 dt][64 lane][4]
    //                    [16384,16640) l_cmb [4 tile][16]
    __shared__ __align__(16) char smem[18432];
    bf16* const pbase = reinterpret_cast<bf16*>(smem);
    float* const o_cmb = reinterpret_cast<float*>(smem);
    float* const l_cmb = reinterpret_cast<float*>(smem + 16384);

    const int lane = threadIdx.x & 63;
    const int wv = threadIdx.x >> 6;  // 0..1 = split-K half
    const int l15 = lane & 15;
    const int g = lane >> 4;

    // bid -> (bh, cq): XCD grouping (all blocks of one bh share bid%8) and
    // longest-first (cq descending in dispatch order). Bijective on [0,1024).
    const int bid = blockIdx.x;
    const int xcd = bid & 7;
    const int idx = bid >> 3;            // 0..127
    const int bh = xcd * 4 + (idx >> 5); // 0..31
    const int cq = 31 - (idx & 31);      // 0..31, longest first
    const int nkb = cq + 1;              // identical for all 4 tiles
    const int qb0t = cq * 64;            // first tile's base row

    const bf16* Qh = Q + (size_t)bh * TT * DH;
    const bf16* Kh = K + (size_t)bh * TT * DH;
    const bf16* Vh = Vt + (size_t)bh * DH * TT;

    bf16x8 qf0[4], qf1[4];
#pragma unroll
    for (int t = 0; t < 4; t++) {
        qf0[t] = load8(Qh + (size_t)(qb0t + t * 16 + l15) * DH + g * 8);
        qf1[t] = load8(Qh + (size_t)(qb0t + t * 16 + l15) * DH + 32 + g * 8);
    }

    f32x4 o[4][4] = {};     // [tile][dt]
    float l[4][4] = {};     // [tile][r]

    bf16* const pw = pbase + wv * 4 * 1152;  // [tile] stride 1152 bf16

    // Prefetch K fragments for this wave's first k-block (k0 = wv*64; rows
    // <=127 always exist so the wv==1,nkb==1 zero-iteration case is safe)
    bf16x8 kf0[4], kf1[4];
#pragma unroll
    for (int j = 0; j < 4; j++) {
        kf0[j] = load8(Kh + (size_t)(wv * 64 + j * 16 + l15) * DH + g * 8);
        kf1[j] = load8(Kh + (size_t)(wv * 64 + j * 16 + l15) * DH + 32 + g * 8);
    }

    for (int kb = wv; kb < nkb; kb += 2) {
        const int k0 = kb * 64;
        const bool last = (kb == nkb - 1);  // diagonal k-block (wave-uniform)

        // ---- V loads (shared by all 4 tiles; skewed addresses) -----------
        bf16x8 vf0[4], vf1[4];
#pragma unroll
        for (int dt = 0; dt < 4; dt++) {
            const int d0 = dt * 16 + l15;
            const int sk = (d0 << 6);
            vf0[dt] = load8(Vh + (size_t)d0 * TT + ((k0 + g * 8 + sk) & (TT - 1)));
            vf1[dt] = load8(Vh + (size_t)d0 * TT + ((k0 + 32 + g * 8 + sk) & (TT - 1)));
        }

        // ---- per tile: QK -> mask -> exp -> stage (S regs reused) --------
#pragma unroll
        for (int t = 0; t < 4; t++) {
            f32x4 S[4] = {};
#pragma unroll
            for (int j = 0; j < 4; j++) {
                S[j] = mfma16(qf0[t], kf0[j], S[j]);
                S[j] = mfma16(qf1[t], kf1[j], S[j]);
            }
            if (last) {
                const int qrow = qb0t + t * 16 + g * 4;
#pragma unroll
                for (int j = 0; j < 4; j++)
#pragma unroll
                    for (int r = 0; r < 4; r++)
                        if (k0 + j * 16 + l15 > qrow + r) S[j][r] = -1e30f;
            }
            bf16* pt = pw + t * 1152;
#pragma unroll
            for (int r = 0; r < 4; r++)
#pragma unroll
                for (int j = 0; j < 4; j++) {
                    const float e = exp2f(S[j][r]);
                    l[t][r] += e;
                    pt[(g * 4 + r) * 72 + j * 16 + l15] = __float2bfloat16(e);
                }
        }

        // ---- K prefetch for this wave's NEXT k-block ---------------------
        if (kb + 2 < nkb) {
            const int kn = k0 + 128;
#pragma unroll
            for (int j = 0; j < 4; j++) {
                kf0[j] = load8(Kh + (size_t)(kn + j * 16 + l15) * DH + g * 8);
                kf1[j] = load8(Kh + (size_t)(kn + j * 16 + l15) * DH + 32 + g * 8);
            }
        }

        // ---- ONE DS fence for all 4 tiles' P writes ----------------------
        asm volatile("s_waitcnt lgkmcnt(0)" ::: "memory");

        // ---- PV per tile (V fragments reused 4x) -------------------------
#pragma unroll
        for (int t = 0; t < 4; t++) {
            const bf16* pt = pw + t * 1152;
            const bf16x8 pf0 = load8(pt + l15 * 72 + g * 8);
            const bf16x8 pf1 = load8(pt + l15 * 72 + 32 + g * 8);
#pragma unroll
            for (int dt = 0; dt < 4; dt++) {
                o[t][dt] = mfma16(pf0, vf0[dt], o[t][dt]);
                o[t][dt] = mfma16(pf1, vf1[dt], o[t][dt]);
            }
        }
    }

    // Per-wave row-sum reduce over the key-lane axis (l15: masks 1,2,4,8).
#pragma unroll
    for (int xm = 1; xm < 16; xm <<= 1) {
#pragma unroll
        for (int t = 0; t < 4; t++)
#pragma unroll
            for (int r = 0; r < 4; r++) l[t][r] += __shfl_xor(l[t][r], xm);
    }

    // All p_lds reads done before o_cmb/l_cmb overlay writes (same smem!)
    __syncthreads();

    // Split-K combine: wave 1 publishes partials; wave 0 merges and writes.
    if (wv == 1) {
#pragma unroll
        for (int t = 0; t < 4; t++) {
#pragma unroll
            for (int dt = 0; dt < 4; dt++)
                *reinterpret_cast<f32x4*>(&o_cmb[((t * 4 + dt) * 64 + lane) * 4]) = o[t][dt];
            if (l15 == 0) {
#pragma unroll
                for (int r = 0; r < 4; r++) l_cmb[t * 16 + g * 4 + r] = l[t][r];
            }
        }
    }
    __syncthreads();
    if (wv == 1) return;

#pragma unroll
    for (int t = 0; t < 4; t++) {
#pragma unroll
        for (int dt = 0; dt < 4; dt++)
            o[t][dt] += *reinterpret_cast<const f32x4*>(&o_cmb[((t * 4 + dt) * 64 + lane) * 4]);
#pragma unroll
        for (int r = 0; r < 4; r++) l[t][r] += l_cmb[t * 16 + g * 4 + r];
    }

    const int b = bh >> 4, h = bh & 15;
#pragma unroll
    for (int t = 0; t < 4; t++) {
#pragma unroll
        for (int r = 0; r < 4; r++) {
            const float inv = 1.0f / l[t][r];
            const int tt = qb0t + t * 16 + g * 4 + r;
            bf16* op = out + (size_t)(b * TT + tt) * CC + h * DH;
#pragma unroll
            for (int dt = 0; dt < 4; dt++)
                op[dt * 16 + l15] = __float2bfloat16(o[t][dt][r] * inv);
        }
    }
}

extern "C" void kernel_launch(void* const* d_in, const int* in_sizes, int n_in,
                              void* d_out, int out_size, void* d_ws, size_t ws_size,
                              hipStream_t stream) {
    const float* x  = (const float*)d_in[0];
    const float* Wq = (const float*)d_in[1];
    const float* Wk = (const float*)d_in[2];
    const float* Wv = (const float*)d_in[3];
    const float* Wo = (const float*)d_in[4];
    float* out = (float*)d_out;  // reference output dtype is float32

    const size_t per = (size_t)BB * HH * TT * DH;  // 4,194,304 elems
    bf16* Qws  = (bf16*)d_ws;       // 8 MB
    bf16* Kws  = Qws + per;         // 8 MB
    bf16* Vtws = Kws + per;         // 8 MB (skewed layout, same footprint)
    bf16* xbf  = Vtws + per;        // 8 MB — attn output aliases (x dead after QKV)
    bf16* attn = xbf;
    bf16* Wball = attn + per;       // 8 MB (4 bf16 weight mats) — needs ws >= 40 MB
    const bool full = ws_size >= 5 * per * sizeof(bf16);

    const dim3 blk(256);
    cvt_x<<<dim3(2048), blk, 0, stream>>>(x, xbf);

    if (full) {
        cvt4_w<<<dim3(512, 4), blk, 0, stream>>>(Wq, Wk, Wv, Wo, Wball);
        gemm3<0><<<dim3(32, 24), blk, 0, stream>>>(
            xbf, Wball, Qws, Kws, Vtws, nullptr);
    } else {
        gemm2<0><<<dim3(32, 24), blk, 0, stream>>>(
            xbf, Wq, Wk, Wv, Qws, Kws, Vtws, nullptr);
    }

    attn_v12<<<dim3(1024), dim3(128), 0, stream>>>(Qws, Kws, Vtws, attn);

    if (full) {
        gemm3<1><<<dim3(32, 8), blk, 0, stream>>>(
            attn, Wball + (size_t)3 * CC * CC, nullptr, nullptr, nullptr, out);
    } else {
        gemm2<1><<<dim3(32, 8), blk, 0, stream>>>(
            attn, Wo, nullptr, nullptr, nullptr, nullptr, nullptr, out);
    }
}

// Round 12
// 236.278 us; speedup vs baseline: 1.1981x; 1.0527x over previous
//
#include <hip/hip_runtime.h>
#include <hip/hip_bf16.h>

#define BB 2
#define TT 2048
#define CC 1024
#define HH 16
#define DH 64

typedef __attribute__((ext_vector_type(8))) short bf16x8;
typedef __attribute__((ext_vector_type(4))) float f32x4;
typedef __attribute__((ext_vector_type(16))) float f32x16;
using bf16 = __hip_bfloat16;
using u32 = unsigned int;

union cvt8u { bf16x8 v; bf16 b[8]; };

__device__ __forceinline__ bf16x8 load8(const bf16* p) {
    return *reinterpret_cast<const bf16x8*>(p);
}

__device__ __forceinline__ bf16x8 cvt8f(const float* p) {
    const float4 a = *reinterpret_cast<const float4*>(p);
    const float4 c = *reinterpret_cast<const float4*>(p + 4);
    cvt8u u;
    u.b[0] = __float2bfloat16(a.x); u.b[1] = __float2bfloat16(a.y);
    u.b[2] = __float2bfloat16(a.z); u.b[3] = __float2bfloat16(a.w);
    u.b[4] = __float2bfloat16(c.x); u.b[5] = __float2bfloat16(c.y);
    u.b[6] = __float2bfloat16(c.z); u.b[7] = __float2bfloat16(c.w);
    return u.v;
}

__device__ __forceinline__ f32x4 mfma16(bf16x8 a, bf16x8 b, f32x4 c) {
    return __builtin_amdgcn_mfma_f32_16x16x32_bf16(a, b, c, 0, 0, 0);
}

__device__ __forceinline__ f32x16 mfma32(bf16x8 a, bf16x8 b, f32x16 c) {
    return __builtin_amdgcn_mfma_f32_32x32x16_bf16(a, b, c, 0, 0, 0);
}

// pack two floats into one u32 of 2 bf16 (compiler emits cvt_pk when it can)
__device__ __forceinline__ u32 pk2(float lo, float hi) {
    union { bf16 b; unsigned short u; } a, c;
    a.b = __float2bfloat16(lo);
    c.b = __float2bfloat16(hi);
    return (u32)a.u | ((u32)c.u << 16);
}

// async global->LDS, 16 B per lane (gemm3 staging). guide §5, m97/m104.
__device__ __forceinline__ void gload_lds16(const bf16* g, bf16* l) {
    __builtin_amdgcn_global_load_lds(
        (const __attribute__((address_space(1))) void*)g,
        (__attribute__((address_space(3))) void*)l, 16, 0, 0);
}

// Q pre-scale: 1/sqrt(64) * log2(e) -> attention uses exp2 directly.
#define QSCALE (0.125f * 1.44269504088896f)

// V^T SKEWED LAYOUT: element (d, t) stored at d*TT + ((t + d*64) & (TT-1)).
// (round 9: perf-neutral, kept — writer and reader consistent.)

// ---------------- fp32 -> bf16 staging kernels ------------------------------
__global__ __launch_bounds__(256) void cvt_x(const float* __restrict__ in,
                                             bf16* __restrict__ out) {
    const int i = blockIdx.x * 256 + threadIdx.x;  // 524288 groups of 8
    *(reinterpret_cast<bf16x8*>(out) + i) = cvt8f(in + (size_t)i * 8);
}

__global__ __launch_bounds__(256) void cvt4_w(const float* __restrict__ w0,
                                              const float* __restrict__ w1,
                                              const float* __restrict__ w2,
                                              const float* __restrict__ w3,
                                              bf16* __restrict__ out) {
    const float* in = (blockIdx.y == 0) ? w0 : (blockIdx.y == 1) ? w1
                    : (blockIdx.y == 2) ? w2 : w3;
    const int i = blockIdx.x * 256 + threadIdx.x;  // 131072 groups of 8 per matrix
    bf16* o = out + (size_t)blockIdx.y * CC * CC;
    *(reinterpret_cast<bf16x8*>(o) + i) = cvt8f(in + (size_t)i * 8);
}

// ---------------- LDS-staged GEMM (m97 structure) ---------------------------
// (unchanged from round 5 — proven. MODE-0 Vt epilogue skewed.)
template <int MODE>
__global__ __launch_bounds__(256) void gemm3(const bf16* __restrict__ A,
                                             const bf16* __restrict__ B,
                                             bf16* __restrict__ oq,
                                             bf16* __restrict__ ok,
                                             bf16* __restrict__ ov,
                                             float* __restrict__ outf) {
    __shared__ __align__(16) bf16 As[128 * 32];  // 8 KB, [row][k] row-major
    __shared__ __align__(16) bf16 Bs[128 * 32];  // 8 KB
    const int lane = threadIdx.x & 63;
    const int wv = threadIdx.x >> 6;
    const int l15 = lane & 15;
    const int g = lane >> 4;
    const int m0 = blockIdx.x * 128;
    const int n0 = blockIdx.y * 128;

    const int srow = wv * 16 + (lane >> 2);
    const int skg = (lane & 3) * 8;
    const bf16* gA0 = A + (size_t)(m0 + srow) * CC + skg;
    const bf16* gA1 = A + (size_t)(m0 + 64 + srow) * CC + skg;
    const bf16* gB0 = B + (size_t)(n0 + srow) * CC + skg;
    const bf16* gB1 = B + (size_t)(n0 + 64 + srow) * CC + skg;
    bf16* lA0 = As + wv * 512;          // wave-uniform LDS bases
    bf16* lA1 = As + 2048 + wv * 512;
    bf16* lB0 = Bs + wv * 512;
    bf16* lB1 = Bs + 2048 + wv * 512;

    const int mw = (wv >> 1) * 64;  // wave's 64x64 sub-tile
    const int nw = (wv & 1) * 64;

    f32x4 acc[4][4] = {};

    for (int kk = 0; kk < CC; kk += 32) {
        __syncthreads();  // previous tile's ds_reads done before overwrite
        gload_lds16(gA0 + kk, lA0);
        gload_lds16(gA1 + kk, lA1);
        gload_lds16(gB0 + kk, lB0);
        gload_lds16(gB1 + kk, lB1);
        __syncthreads();  // vmcnt(0) drained before s_barrier -> tile ready

        bf16x8 af[4], wf[4];
#pragma unroll
        for (int mi = 0; mi < 4; mi++)
            af[mi] = load8(As + (mw + mi * 16 + l15) * 32 + g * 8);
#pragma unroll
        for (int ni = 0; ni < 4; ni++)
            wf[ni] = load8(Bs + (nw + ni * 16 + l15) * 32 + g * 8);
#pragma unroll
        for (int mi = 0; mi < 4; mi++)
#pragma unroll
            for (int ni = 0; ni < 4; ni++)
                acc[mi][ni] = mfma16(af[mi], wf[ni], acc[mi][ni]);
    }

#pragma unroll
    for (int mi = 0; mi < 4; mi++) {
#pragma unroll
        for (int ni = 0; ni < 4; ni++) {
            const int n = n0 + nw + ni * 16 + l15;  // C/D: col = lane&15
#pragma unroll
            for (int r = 0; r < 4; r++) {
                const int m = m0 + mw + mi * 16 + g * 4 + r;  // row=(lane>>4)*4+reg
                const float v = acc[mi][ni][r];
                if (MODE == 1) {
                    outf[(size_t)m * CC + n] = v;  // d_out is FLOAT32
                } else {
                    const int b = m >> 11, t = m & (TT - 1);
                    const int mat = n >> 10, nn = n & 1023;
                    const int h = nn >> 6, d = nn & 63;
                    if (mat == 0) {
                        oq[((size_t)((b * HH + h) * TT + t) << 6) + d] = __float2bfloat16(v * QSCALE);
                    } else if (mat == 1) {
                        ok[((size_t)((b * HH + h) * TT + t) << 6) + d] = __float2bfloat16(v);
                    } else {
                        // skewed V^T store (see layout comment above)
                        ov[(size_t)((b * HH + h) * DH + d) * TT + ((t + (d << 6)) & (TT - 1))] = __float2bfloat16(v);
                    }
                }
            }
        }
    }
}

// ---------------- register-direct GEMM (fallback, fp32 weights) -------------
template <int MODE>
__global__ __launch_bounds__(256) void gemm2(const bf16* __restrict__ A,
                                             const float* __restrict__ W0,
                                             const float* __restrict__ W1,
                                             const float* __restrict__ W2,
                                             bf16* __restrict__ oq,
                                             bf16* __restrict__ ok,
                                             bf16* __restrict__ ov,
                                             float* __restrict__ outf) {
    const int lane = threadIdx.x & 63;
    const int wv = threadIdx.x >> 6;
    const int l15 = lane & 15;
    const int g = lane >> 4;
    const int mw = blockIdx.x * 128 + (wv >> 1) * 64;
    const int nw = blockIdx.y * 128 + (wv & 1) * 64;

    f32x4 acc[4][4] = {};

    const bf16* ap[4];
#pragma unroll
    for (int mi = 0; mi < 4; mi++)
        ap[mi] = A + (size_t)(mw + mi * 16 + l15) * CC + g * 8;

    const float* wfp[4];
#pragma unroll
    for (int ni = 0; ni < 4; ni++) {
        const int nt = nw + ni * 16;
        const float* base = (MODE == 1) ? W0
                          : (nt < 1024) ? W0 : (nt < 2048) ? W1 : W2;
        wfp[ni] = base + (size_t)((nt & 1023) + l15) * CC + g * 8;
    }

#pragma unroll 2
    for (int kk = 0; kk < CC; kk += 32) {
        bf16x8 af[4], wf[4];
#pragma unroll
        for (int mi = 0; mi < 4; mi++) af[mi] = load8(ap[mi] + kk);
#pragma unroll
        for (int ni = 0; ni < 4; ni++) wf[ni] = cvt8f(wfp[ni] + kk);
#pragma unroll
        for (int mi = 0; mi < 4; mi++)
#pragma unroll
            for (int ni = 0; ni < 4; ni++)
                acc[mi][ni] = mfma16(af[mi], wf[ni], acc[mi][ni]);
    }

#pragma unroll
    for (int mi = 0; mi < 4; mi++) {
#pragma unroll
        for (int ni = 0; ni < 4; ni++) {
            const int n = nw + ni * 16 + l15;
#pragma unroll
            for (int r = 0; r < 4; r++) {
                const int m = mw + mi * 16 + g * 4 + r;
                const float v = acc[mi][ni][r];
                if (MODE == 1) {
                    outf[(size_t)m * CC + n] = v;
                } else {
                    const int b = m >> 11, t = m & (TT - 1);
                    const int mat = n >> 10, nn = n & 1023;
                    const int h = nn >> 6, d = nn & 63;
                    if (mat == 0) {
                        oq[((size_t)((b * HH + h) * TT + t) << 6) + d] = __float2bfloat16(v * QSCALE);
                    } else if (mat == 1) {
                        ok[((size_t)((b * HH + h) * TT + t) << 6) + d] = __float2bfloat16(v);
                    } else {
                        ov[(size_t)((b * HH + h) * DH + d) * TT + ((t + (d << 6)) & (TT - 1))] = __float2bfloat16(v);
                    }
                }
            }
        }
    }
}

// ---------------- MFMA flash attention v13 ----------------------------------
// ESCAPE FROM THE 107us PLATEAU (rounds 4-11: scheduling-invariant at 161 TF,
// = the documented 1-wave 16x16 structural plateau). v13 adopts the 32x32
// swapped-QK^T structure: S^T = mfma32(K, Q) puts q IN THE LANE and key IN
// THE REGISTER (C/D: col=lane&31, row=(r&3)+8*(r>>2)+4*(lane>>5), verified
// m74/m101) -> mask/exp2/row-sum are lane-local VALU. P -> PV-A-operand needs
// only a half-exchange: pack key-pairs to bf16 (8 words), shfl_xor(32) (8),
// half-dependent select (8 cndmask). PV-B reads the skewed V^T directly
// (rows of V^T are key-contiguous). ZERO LDS / fences / barriers in the main
// loop — the old serial core (32 ds_write_b16 + lgkmcnt drain + ds_read)
// is gone. Split-K x2 kept: block = one 32-row q-tile, 2 waves stride 32-key
// blocks by parity, LDS combine once at the end. 2048 blocks x 128 thr.
__global__ __launch_bounds__(128, 2) void attn_v13(const bf16* __restrict__ Q,
                                                   const bf16* __restrict__ K,
                                                   const bf16* __restrict__ Vt,
                                                   bf16* __restrict__ out) {
    __shared__ __align__(64) float o_cmb[2][64][16];  // 8 KB
    __shared__ float l_cmb[32];                       // 128 B

    const int lane = threadIdx.x & 63;
    const int wv = threadIdx.x >> 6;   // 0..1 = split-K half
    const int l31 = lane & 31;
    const int hh = lane >> 5;          // 0..1 = lane half

    // bid -> (bh, c): XCD grouping (all 64 tiles of a bh share bid%8) +
    // longest-first (c descending). Bijective on [0,2048).
    const int bid = blockIdx.x;
    const int xcd = bid & 7;
    const int idx = bid >> 3;            // 0..255
    const int bh = xcd * 4 + (idx >> 6); // 0..31
    const int c = 63 - (idx & 63);       // 0..63, longest first
    const int qb = c * 32;               // q rows [qb, qb+32)
    // keys needed: 0 .. qb+31 -> 32-key blocks 0..c

    const bf16* Qh = Q + (size_t)bh * TT * DH;
    const bf16* Kh = K + (size_t)bh * TT * DH;
    const bf16* Vh = Vt + (size_t)bh * DH * TT;

    // Q fragments (B-operand of swapped QK): col=q=l31, k=d=hh*8+i, 4 chunks
    bf16x8 qf[4];
#pragma unroll
    for (int dc = 0; dc < 4; dc++)
        qf[dc] = load8(Qh + (size_t)(qb + l31) * DH + dc * 16 + hh * 8);

    f32x16 o0 = {}, o1 = {};   // O accum: [d-tile 0: d=l31][d-tile 1: d=32+l31]
    float l_part = 0.0f;       // sum of exp over this lane's keys (q=l31 slice)

    const int qlane = qb + l31;

    for (int kb = wv; kb <= c; kb += 2) {
        const int k0 = kb * 32;

        // ---- V fragments for PV (B-operand): col=d=l31(+32), k=key=hh*8+i.
        // Skewed V^T rows are key-contiguous.
        bf16x8 vf00, vf01, vf10, vf11;  // [dt][ks]
        {
            const int d0 = l31, d1 = 32 + l31;
            const int s0 = d0 << 6, s1 = d1 << 6;
            vf00 = load8(Vh + (size_t)d0 * TT + ((k0 + hh * 8 + s0) & (TT - 1)));
            vf01 = load8(Vh + (size_t)d0 * TT + ((k0 + 16 + hh * 8 + s0) & (TT - 1)));
            vf10 = load8(Vh + (size_t)d1 * TT + ((k0 + hh * 8 + s1) & (TT - 1)));
            vf11 = load8(Vh + (size_t)d1 * TT + ((k0 + 16 + hh * 8 + s1) & (TT - 1)));
        }

        // ---- K fragments (A-operand): row=key=l31, k=d=hh*8+i, 4 chunks
        bf16x8 kf[4];
#pragma unroll
        for (int dc = 0; dc < 4; dc++)
            kf[dc] = load8(Kh + (size_t)(k0 + l31) * DH + dc * 16 + hh * 8);

        // ---- S^T = K . Q^T over D=64 (4 mfma, one accumulator) -----------
        f32x16 S = {};
#pragma unroll
        for (int dc = 0; dc < 4; dc++) S = mfma32(kf[dc], qf[dc], S);

        // ---- causal mask (diagonal block only; key index = c_r + 4*hh) ---
        if (kb == c) {
#pragma unroll
            for (int r = 0; r < 16; r++) {
                const int c_r = (r & 3) + 8 * (r >> 2);
                if (k0 + c_r + 4 * hh > qlane) S[r] = -1e30f;
            }
        }

        // ---- exp2 (Q pre-scaled by log2e) + lane-local row-sum -----------
        float e[16];
#pragma unroll
        for (int r = 0; r < 16; r++) {
            e[r] = exp2f(S[r]);
            l_part += e[r];
        }

        // ---- pack P to bf16 pairs; half-exchange; build PV A-frags -------
        // lane (q=l31, hh) holds keys {(r&3)+8*(r>>2)+4hh}; A-operand wants
        // keys hh*8..hh*8+7 (frag1: local 0..15) / 16+hh*8.. (frag2).
        u32 w0 = pk2(e[0], e[1]),   w1 = pk2(e[2], e[3]);
        u32 w2 = pk2(e[4], e[5]),   w3 = pk2(e[6], e[7]);
        u32 w4 = pk2(e[8], e[9]),   w5 = pk2(e[10], e[11]);
        u32 w6 = pk2(e[12], e[13]), w7 = pk2(e[14], e[15]);
        const u32 x0 = __shfl_xor(w0, 32), x1 = __shfl_xor(w1, 32);
        const u32 x2 = __shfl_xor(w2, 32), x3 = __shfl_xor(w3, 32);
        const u32 x4 = __shfl_xor(w4, 32), x5 = __shfl_xor(w5, 32);
        const u32 x6 = __shfl_xor(w6, 32), x7 = __shfl_xor(w7, 32);

        union { u32 u[4]; bf16x8 v; } a1, a2;
        a1.u[0] = hh ? x2 : w0;  a1.u[1] = hh ? x3 : w1;
        a1.u[2] = hh ? w2 : x0;  a1.u[3] = hh ? w3 : x1;
        a2.u[0] = hh ? x6 : w4;  a2.u[1] = hh ? x7 : w5;
        a2.u[2] = hh ? w6 : x4;  a2.u[3] = hh ? w7 : x5;

        // ---- PV: O[q][d] += P[q][key16] . V[key16][d32]  (4 mfma) --------
        o0 = mfma32(a1.v, vf00, o0);
        o0 = mfma32(a2.v, vf01, o0);
        o1 = mfma32(a1.v, vf10, o1);
        o1 = mfma32(a2.v, vf11, o1);
    }

    // Fold the two lane-halves of the row sum: both halves of q=l31 add up.
    l_part += __shfl_xor(l_part, 32);

    // ---- split-K combine (one barrier) -----------------------------------
    if (wv == 1) {
        *reinterpret_cast<f32x16*>(&o_cmb[0][lane][0]) = o0;
        *reinterpret_cast<f32x16*>(&o_cmb[1][lane][0]) = o1;
        if (lane < 32) l_cmb[lane] = l_part;
    }
    __syncthreads();
    if (wv == 1) return;

    o0 += *reinterpret_cast<const f32x16*>(&o_cmb[0][lane][0]);
    o1 += *reinterpret_cast<const f32x16*>(&o_cmb[1][lane][0]);
    const float linv = 1.0f / (l_part + l_cmb[l31]);  // lane q=l31 (both halves)

    const int b = bh >> 4, h = bh & 15;
#pragma unroll
    for (int r = 0; r < 16; r++) {
        const int qrow = (r & 3) + 8 * (r >> 2) + 4 * hh;   // C/D row -> q
        const float inv = __shfl(linv, qrow);               // lane qrow holds it
        const int t = qb + qrow;
        bf16* op = out + (size_t)(b * TT + t) * CC + h * DH;
        op[l31] = __float2bfloat16(o0[r] * inv);
        op[32 + l31] = __float2bfloat16(o1[r] * inv);
    }
}

extern "C" void kernel_launch(void* const* d_in, const int* in_sizes, int n_in,
                              void* d_out, int out_size, void* d_ws, size_t ws_size,
                              hipStream_t stream) {
    const float* x  = (const float*)d_in[0];
    const float* Wq = (const float*)d_in[1];
    const float* Wk = (const float*)d_in[2];
    const float* Wv = (const float*)d_in[3];
    const float* Wo = (const float*)d_in[4];
    float* out = (float*)d_out;  // reference output dtype is float32

    const size_t per = (size_t)BB * HH * TT * DH;  // 4,194,304 elems
    bf16* Qws  = (bf16*)d_ws;       // 8 MB
    bf16* Kws  = Qws + per;         // 8 MB
    bf16* Vtws = Kws + per;         // 8 MB (skewed layout)
    bf16* xbf  = Vtws + per;        // 8 MB — attn output aliases (x dead after QKV)
    bf16* attn = xbf;
    bf16* Wball = attn + per;       // 8 MB (4 bf16 weight mats) — needs ws >= 40 MB
    const bool full = ws_size >= 5 * per * sizeof(bf16);

    const dim3 blk(256);
    cvt_x<<<dim3(2048), blk, 0, stream>>>(x, xbf);

    if (full) {
        cvt4_w<<<dim3(512, 4), blk, 0, stream>>>(Wq, Wk, Wv, Wo, Wball);
        gemm3<0><<<dim3(32, 24), blk, 0, stream>>>(
            xbf, Wball, Qws, Kws, Vtws, nullptr);
    } else {
        gemm2<0><<<dim3(32, 24), blk, 0, stream>>>(
            xbf, Wq, Wk, Wv, Qws, Kws, Vtws, nullptr);
    }

    attn_v13<<<dim3(2048), dim3(128), 0, stream>>>(Qws, Kws, Vtws, attn);

    if (full) {
        gemm3<1><<<dim3(32, 8), blk, 0, stream>>>(
            attn, Wball + (size_t)3 * CC * CC, nullptr, nullptr, nullptr, out);
    } else {
        gemm2<1><<<dim3(32, 8), blk, 0, stream>>>(
            attn, Wo, nullptr, nullptr, nullptr, nullptr, nullptr, out);
    }
}

// Round 13
// 221.807 us; speedup vs baseline: 1.2762x; 1.0652x over previous
//
#include <hip/hip_runtime.h>
#include <hip/hip_bf16.h>

#define BB 2
#define TT 2048
#define CC 1024
#define HH 16
#define DH 64

typedef __attribute__((ext_vector_type(8))) short bf16x8;
typedef __attribute__((ext_vector_type(4))) float f32x4;
typedef __attribute__((ext_vector_type(16))) float f32x16;
using bf16 = __hip_bfloat16;
using u32 = unsigned int;

union cvt8u { bf16x8 v; bf16 b[8]; };

__device__ __forceinline__ bf16x8 load8(const bf16* p) {
    return *reinterpret_cast<const bf16x8*>(p);
}

__device__ __forceinline__ bf16x8 cvt8f(const float* p) {
    const float4 a = *reinterpret_cast<const float4*>(p);
    const float4 c = *reinterpret_cast<const float4*>(p + 4);
    cvt8u u;
    u.b[0] = __float2bfloat16(a.x); u.b[1] = __float2bfloat16(a.y);
    u.b[2] = __float2bfloat16(a.z); u.b[3] = __float2bfloat16(a.w);
    u.b[4] = __float2bfloat16(c.x); u.b[5] = __float2bfloat16(c.y);
    u.b[6] = __float2bfloat16(c.z); u.b[7] = __float2bfloat16(c.w);
    return u.v;
}

__device__ __forceinline__ f32x4 mfma16(bf16x8 a, bf16x8 b, f32x4 c) {
    return __builtin_amdgcn_mfma_f32_16x16x32_bf16(a, b, c, 0, 0, 0);
}

__device__ __forceinline__ f32x16 mfma32(bf16x8 a, bf16x8 b, f32x16 c) {
    return __builtin_amdgcn_mfma_f32_32x32x16_bf16(a, b, c, 0, 0, 0);
}

// pack two floats into one u32 of 2 bf16
__device__ __forceinline__ u32 pk2(float lo, float hi) {
    union { bf16 b; unsigned short u; } a, c;
    a.b = __float2bfloat16(lo);
    c.b = __float2bfloat16(hi);
    return (u32)a.u | ((u32)c.u << 16);
}

// async global->LDS, 16 B per lane (gemm3 staging). guide §5, m97/m104.
__device__ __forceinline__ void gload_lds16(const bf16* g, bf16* l) {
    __builtin_amdgcn_global_load_lds(
        (const __attribute__((address_space(1))) void*)g,
        (__attribute__((address_space(3))) void*)l, 16, 0, 0);
}

// Q pre-scale: 1/sqrt(64) * log2(e) -> attention uses exp2 directly.
#define QSCALE (0.125f * 1.44269504088896f)

// V^T SKEWED LAYOUT: element (d, t) stored at d*TT + ((t + d*64) & (TT-1)).

// ---------------- fp32 -> bf16 staging kernels ------------------------------
__global__ __launch_bounds__(256) void cvt_x(const float* __restrict__ in,
                                             bf16* __restrict__ out) {
    const int i = blockIdx.x * 256 + threadIdx.x;  // 524288 groups of 8
    *(reinterpret_cast<bf16x8*>(out) + i) = cvt8f(in + (size_t)i * 8);
}

__global__ __launch_bounds__(256) void cvt4_w(const float* __restrict__ w0,
                                              const float* __restrict__ w1,
                                              const float* __restrict__ w2,
                                              const float* __restrict__ w3,
                                              bf16* __restrict__ out) {
    const float* in = (blockIdx.y == 0) ? w0 : (blockIdx.y == 1) ? w1
                    : (blockIdx.y == 2) ? w2 : w3;
    const int i = blockIdx.x * 256 + threadIdx.x;  // 131072 groups of 8 per matrix
    bf16* o = out + (size_t)blockIdx.y * CC * CC;
    *(reinterpret_cast<bf16x8*>(o) + i) = cvt8f(in + (size_t)i * 8);
}

// ---------------- LDS-staged GEMM (m97 structure) ---------------------------
// (unchanged from round 5 — proven. MODE-0 Vt epilogue skewed.)
template <int MODE>
__global__ __launch_bounds__(256) void gemm3(const bf16* __restrict__ A,
                                             const bf16* __restrict__ B,
                                             bf16* __restrict__ oq,
                                             bf16* __restrict__ ok,
                                             bf16* __restrict__ ov,
                                             float* __restrict__ outf) {
    __shared__ __align__(16) bf16 As[128 * 32];  // 8 KB, [row][k] row-major
    __shared__ __align__(16) bf16 Bs[128 * 32];  // 8 KB
    const int lane = threadIdx.x & 63;
    const int wv = threadIdx.x >> 6;
    const int l15 = lane & 15;
    const int g = lane >> 4;
    const int m0 = blockIdx.x * 128;
    const int n0 = blockIdx.y * 128;

    const int srow = wv * 16 + (lane >> 2);
    const int skg = (lane & 3) * 8;
    const bf16* gA0 = A + (size_t)(m0 + srow) * CC + skg;
    const bf16* gA1 = A + (size_t)(m0 + 64 + srow) * CC + skg;
    const bf16* gB0 = B + (size_t)(n0 + srow) * CC + skg;
    const bf16* gB1 = B + (size_t)(n0 + 64 + srow) * CC + skg;
    bf16* lA0 = As + wv * 512;          // wave-uniform LDS bases
    bf16* lA1 = As + 2048 + wv * 512;
    bf16* lB0 = Bs + wv * 512;
    bf16* lB1 = Bs + 2048 + wv * 512;

    const int mw = (wv >> 1) * 64;  // wave's 64x64 sub-tile
    const int nw = (wv & 1) * 64;

    f32x4 acc[4][4] = {};

    for (int kk = 0; kk < CC; kk += 32) {
        __syncthreads();  // previous tile's ds_reads done before overwrite
        gload_lds16(gA0 + kk, lA0);
        gload_lds16(gA1 + kk, lA1);
        gload_lds16(gB0 + kk, lB0);
        gload_lds16(gB1 + kk, lB1);
        __syncthreads();  // vmcnt(0) drained before s_barrier -> tile ready

        bf16x8 af[4], wf[4];
#pragma unroll
        for (int mi = 0; mi < 4; mi++)
            af[mi] = load8(As + (mw + mi * 16 + l15) * 32 + g * 8);
#pragma unroll
        for (int ni = 0; ni < 4; ni++)
            wf[ni] = load8(Bs + (nw + ni * 16 + l15) * 32 + g * 8);
#pragma unroll
        for (int mi = 0; mi < 4; mi++)
#pragma unroll
            for (int ni = 0; ni < 4; ni++)
                acc[mi][ni] = mfma16(af[mi], wf[ni], acc[mi][ni]);
    }

#pragma unroll
    for (int mi = 0; mi < 4; mi++) {
#pragma unroll
        for (int ni = 0; ni < 4; ni++) {
            const int n = n0 + nw + ni * 16 + l15;  // C/D: col = lane&15
#pragma unroll
            for (int r = 0; r < 4; r++) {
                const int m = m0 + mw + mi * 16 + g * 4 + r;  // row=(lane>>4)*4+reg
                const float v = acc[mi][ni][r];
                if (MODE == 1) {
                    outf[(size_t)m * CC + n] = v;  // d_out is FLOAT32
                } else {
                    const int b = m >> 11, t = m & (TT - 1);
                    const int mat = n >> 10, nn = n & 1023;
                    const int h = nn >> 6, d = nn & 63;
                    if (mat == 0) {
                        oq[((size_t)((b * HH + h) * TT + t) << 6) + d] = __float2bfloat16(v * QSCALE);
                    } else if (mat == 1) {
                        ok[((size_t)((b * HH + h) * TT + t) << 6) + d] = __float2bfloat16(v);
                    } else {
                        // skewed V^T store (see layout comment above)
                        ov[(size_t)((b * HH + h) * DH + d) * TT + ((t + (d << 6)) & (TT - 1))] = __float2bfloat16(v);
                    }
                }
            }
        }
    }
}

// ---------------- register-direct GEMM (fallback, fp32 weights) -------------
template <int MODE>
__global__ __launch_bounds__(256) void gemm2(const bf16* __restrict__ A,
                                             const float* __restrict__ W0,
                                             const float* __restrict__ W1,
                                             const float* __restrict__ W2,
                                             bf16* __restrict__ oq,
                                             bf16* __restrict__ ok,
                                             bf16* __restrict__ ov,
                                             float* __restrict__ outf) {
    const int lane = threadIdx.x & 63;
    const int wv = threadIdx.x >> 6;
    const int l15 = lane & 15;
    const int g = lane >> 4;
    const int mw = blockIdx.x * 128 + (wv >> 1) * 64;
    const int nw = blockIdx.y * 128 + (wv & 1) * 64;

    f32x4 acc[4][4] = {};

    const bf16* ap[4];
#pragma unroll
    for (int mi = 0; mi < 4; mi++)
        ap[mi] = A + (size_t)(mw + mi * 16 + l15) * CC + g * 8;

    const float* wfp[4];
#pragma unroll
    for (int ni = 0; ni < 4; ni++) {
        const int nt = nw + ni * 16;
        const float* base = (MODE == 1) ? W0
                          : (nt < 1024) ? W0 : (nt < 2048) ? W1 : W2;
        wfp[ni] = base + (size_t)((nt & 1023) + l15) * CC + g * 8;
    }

#pragma unroll 2
    for (int kk = 0; kk < CC; kk += 32) {
        bf16x8 af[4], wf[4];
#pragma unroll
        for (int mi = 0; mi < 4; mi++) af[mi] = load8(ap[mi] + kk);
#pragma unroll
        for (int ni = 0; ni < 4; ni++) wf[ni] = cvt8f(wfp[ni] + kk);
#pragma unroll
        for (int mi = 0; mi < 4; mi++)
#pragma unroll
            for (int ni = 0; ni < 4; ni++)
                acc[mi][ni] = mfma16(af[mi], wf[ni], acc[mi][ni]);
    }

#pragma unroll
    for (int mi = 0; mi < 4; mi++) {
#pragma unroll
        for (int ni = 0; ni < 4; ni++) {
            const int n = nw + ni * 16 + l15;
#pragma unroll
            for (int r = 0; r < 4; r++) {
                const int m = mw + mi * 16 + g * 4 + r;
                const float v = acc[mi][ni][r];
                if (MODE == 1) {
                    outf[(size_t)m * CC + n] = v;
                } else {
                    const int b = m >> 11, t = m & (TT - 1);
                    const int mat = n >> 10, nn = n & 1023;
                    const int h = nn >> 6, d = nn & 63;
                    if (mat == 0) {
                        oq[((size_t)((b * HH + h) * TT + t) << 6) + d] = __float2bfloat16(v * QSCALE);
                    } else if (mat == 1) {
                        ok[((size_t)((b * HH + h) * TT + t) << 6) + d] = __float2bfloat16(v);
                    } else {
                        ov[(size_t)((b * HH + h) * DH + d) * TT + ((t + (d << 6)) & (TT - 1))] = __float2bfloat16(v);
                    }
                }
            }
        }
    }
}

// ---------------- MFMA flash attention v14 ----------------------------------
// v13 (32x32 swapped-QK^T, in-register softmax, zero LDS in loop) verified
// correct and cut 107 -> 99.7us, but iteration wall is still ~920 cyc vs
// ~250 issue: v13 loads K AND V at the top of each iteration and consumes
// them immediately — naked L2 latency, ~1.8 waves/SIMD can't hide it (VGPR
// was only 60!). v14 = v13 + depth-1 K/V prefetch: next iteration's 8 loads
// issue BEFORE this iteration's QK, giving them a full iteration of
// MFMA+VALU to land under. Cost: +64 VGPR double-buffer (~130 total, still
// 3 waves/SIMD, no spill).
__global__ __launch_bounds__(128, 2) void attn_v14(const bf16* __restrict__ Q,
                                                   const bf16* __restrict__ K,
                                                   const bf16* __restrict__ Vt,
                                                   bf16* __restrict__ out) {
    __shared__ __align__(64) float o_cmb[2][64][16];  // 8 KB
    __shared__ float l_cmb[32];                       // 128 B

    const int lane = threadIdx.x & 63;
    const int wv = threadIdx.x >> 6;   // 0..1 = split-K half
    const int l31 = lane & 31;
    const int hh = lane >> 5;          // 0..1 = lane half

    // bid -> (bh, c): XCD grouping + longest-first. Bijective on [0,2048).
    const int bid = blockIdx.x;
    const int xcd = bid & 7;
    const int idx = bid >> 3;            // 0..255
    const int bh = xcd * 4 + (idx >> 6); // 0..31
    const int c = 63 - (idx & 63);       // 0..63, longest first
    const int qb = c * 32;               // q rows [qb, qb+32)

    const bf16* Qh = Q + (size_t)bh * TT * DH;
    const bf16* Kh = K + (size_t)bh * TT * DH;
    const bf16* Vh = Vt + (size_t)bh * DH * TT;

    // Q fragments (B-operand of swapped QK): col=q=l31, k=d=hh*8+i, 4 chunks
    bf16x8 qf[4];
#pragma unroll
    for (int dc = 0; dc < 4; dc++)
        qf[dc] = load8(Qh + (size_t)(qb + l31) * DH + dc * 16 + hh * 8);

    f32x16 o0 = {}, o1 = {};   // O accum: [d=l31] and [d=32+l31]
    float l_part = 0.0f;

    const int qlane = qb + l31;
    const int d0 = l31, d1 = 32 + l31;
    const int s0 = d0 << 6, s1 = d1 << 6;

    // ---- initial K/V fragments for kb = wv (rows 32..63 exist even when
    // wave 1 runs zero iterations — safe) --------------------------------
    bf16x8 kf[4], vf00, vf01, vf10, vf11;
    {
        const int k0 = wv * 32;
#pragma unroll
        for (int dc = 0; dc < 4; dc++)
            kf[dc] = load8(Kh + (size_t)(k0 + l31) * DH + dc * 16 + hh * 8);
        vf00 = load8(Vh + (size_t)d0 * TT + ((k0 + hh * 8 + s0) & (TT - 1)));
        vf01 = load8(Vh + (size_t)d0 * TT + ((k0 + 16 + hh * 8 + s0) & (TT - 1)));
        vf10 = load8(Vh + (size_t)d1 * TT + ((k0 + hh * 8 + s1) & (TT - 1)));
        vf11 = load8(Vh + (size_t)d1 * TT + ((k0 + 16 + hh * 8 + s1) & (TT - 1)));
    }

    for (int kb = wv; kb <= c; kb += 2) {
        const int k0 = kb * 32;
        const bool more = (kb + 2 <= c);  // wave-uniform

        // ---- prefetch NEXT iteration's K/V (lands under this iter's work)
        bf16x8 kfn[4], vn00, vn01, vn10, vn11;
        if (more) {
            const int kn = k0 + 64;
#pragma unroll
            for (int dc = 0; dc < 4; dc++)
                kfn[dc] = load8(Kh + (size_t)(kn + l31) * DH + dc * 16 + hh * 8);
            vn00 = load8(Vh + (size_t)d0 * TT + ((kn + hh * 8 + s0) & (TT - 1)));
            vn01 = load8(Vh + (size_t)d0 * TT + ((kn + 16 + hh * 8 + s0) & (TT - 1)));
            vn10 = load8(Vh + (size_t)d1 * TT + ((kn + hh * 8 + s1) & (TT - 1)));
            vn11 = load8(Vh + (size_t)d1 * TT + ((kn + 16 + hh * 8 + s1) & (TT - 1)));
        }

        // ---- S^T = K . Q^T over D=64 (4 mfma, one accumulator) -----------
        f32x16 S = {};
#pragma unroll
        for (int dc = 0; dc < 4; dc++) S = mfma32(kf[dc], qf[dc], S);

        // ---- causal mask (diagonal block only; key index = c_r + 4*hh) ---
        if (kb == c) {
#pragma unroll
            for (int r = 0; r < 16; r++) {
                const int c_r = (r & 3) + 8 * (r >> 2);
                if (k0 + c_r + 4 * hh > qlane) S[r] = -1e30f;
            }
        }

        // ---- exp2 (Q pre-scaled by log2e) + lane-local row-sum -----------
        float e[16];
#pragma unroll
        for (int r = 0; r < 16; r++) {
            e[r] = exp2f(S[r]);
            l_part += e[r];
        }

        // ---- pack P to bf16 pairs; half-exchange; build PV A-frags -------
        u32 w0 = pk2(e[0], e[1]),   w1 = pk2(e[2], e[3]);
        u32 w2 = pk2(e[4], e[5]),   w3 = pk2(e[6], e[7]);
        u32 w4 = pk2(e[8], e[9]),   w5 = pk2(e[10], e[11]);
        u32 w6 = pk2(e[12], e[13]), w7 = pk2(e[14], e[15]);
        const u32 x0 = __shfl_xor(w0, 32), x1 = __shfl_xor(w1, 32);
        const u32 x2 = __shfl_xor(w2, 32), x3 = __shfl_xor(w3, 32);
        const u32 x4 = __shfl_xor(w4, 32), x5 = __shfl_xor(w5, 32);
        const u32 x6 = __shfl_xor(w6, 32), x7 = __shfl_xor(w7, 32);

        union { u32 u[4]; bf16x8 v; } a1, a2;
        a1.u[0] = hh ? x2 : w0;  a1.u[1] = hh ? x3 : w1;
        a1.u[2] = hh ? w2 : x0;  a1.u[3] = hh ? w3 : x1;
        a2.u[0] = hh ? x6 : w4;  a2.u[1] = hh ? x7 : w5;
        a2.u[2] = hh ? w6 : x4;  a2.u[3] = hh ? w7 : x5;

        // ---- PV: O[q][d] += P[q][key16] . V[key16][d32]  (4 mfma) --------
        o0 = mfma32(a1.v, vf00, o0);
        o0 = mfma32(a2.v, vf01, o0);
        o1 = mfma32(a1.v, vf10, o1);
        o1 = mfma32(a2.v, vf11, o1);

        // ---- rotate double buffers ---------------------------------------
        if (more) {
#pragma unroll
            for (int dc = 0; dc < 4; dc++) kf[dc] = kfn[dc];
            vf00 = vn00; vf01 = vn01; vf10 = vn10; vf11 = vn11;
        }
    }

    // Fold the two lane-halves of the row sum.
    l_part += __shfl_xor(l_part, 32);

    // ---- split-K combine (one barrier) -----------------------------------
    if (wv == 1) {
        *reinterpret_cast<f32x16*>(&o_cmb[0][lane][0]) = o0;
        *reinterpret_cast<f32x16*>(&o_cmb[1][lane][0]) = o1;
        if (lane < 32) l_cmb[lane] = l_part;
    }
    __syncthreads();
    if (wv == 1) return;

    o0 += *reinterpret_cast<const f32x16*>(&o_cmb[0][lane][0]);
    o1 += *reinterpret_cast<const f32x16*>(&o_cmb[1][lane][0]);
    const float linv = 1.0f / (l_part + l_cmb[l31]);

    const int b = bh >> 4, h = bh & 15;
#pragma unroll
    for (int r = 0; r < 16; r++) {
        const int qrow = (r & 3) + 8 * (r >> 2) + 4 * hh;   // C/D row -> q
        const float inv = __shfl(linv, qrow);               // lane qrow holds it
        const int t = qb + qrow;
        bf16* op = out + (size_t)(b * TT + t) * CC + h * DH;
        op[l31] = __float2bfloat16(o0[r] * inv);
        op[32 + l31] = __float2bfloat16(o1[r] * inv);
    }
}

extern "C" void kernel_launch(void* const* d_in, const int* in_sizes, int n_in,
                              void* d_out, int out_size, void* d_ws, size_t ws_size,
                              hipStream_t stream) {
    const float* x  = (const float*)d_in[0];
    const float* Wq = (const float*)d_in[1];
    const float* Wk = (const float*)d_in[2];
    const float* Wv = (const float*)d_in[3];
    const float* Wo = (const float*)d_in[4];
    float* out = (float*)d_out;  // reference output dtype is float32

    const size_t per = (size_t)BB * HH * TT * DH;  // 4,194,304 elems
    bf16* Qws  = (bf16*)d_ws;       // 8 MB
    bf16* Kws  = Qws + per;         // 8 MB
    bf16* Vtws = Kws + per;         // 8 MB (skewed layout)
    bf16* xbf  = Vtws + per;        // 8 MB — attn output aliases (x dead after QKV)
    bf16* attn = xbf;
    bf16* Wball = attn + per;       // 8 MB (4 bf16 weight mats) — needs ws >= 40 MB
    const bool full = ws_size >= 5 * per * sizeof(bf16);

    const dim3 blk(256);
    cvt_x<<<dim3(2048), blk, 0, stream>>>(x, xbf);

    if (full) {
        cvt4_w<<<dim3(512, 4), blk, 0, stream>>>(Wq, Wk, Wv, Wo, Wball);
        gemm3<0><<<dim3(32, 24), blk, 0, stream>>>(
            xbf, Wball, Qws, Kws, Vtws, nullptr);
    } else {
        gemm2<0><<<dim3(32, 24), blk, 0, stream>>>(
            xbf, Wq, Wk, Wv, Qws, Kws, Vtws, nullptr);
    }

    attn_v14<<<dim3(2048), dim3(128), 0, stream>>>(Qws, Kws, Vtws, attn);

    if (full) {
        gemm3<1><<<dim3(32, 8), blk, 0, stream>>>(
            attn, Wball + (size_t)3 * CC * CC, nullptr, nullptr, nullptr, out);
    } else {
        gemm2<1><<<dim3(32, 8), blk, 0, stream>>>(
            attn, Wo, nullptr, nullptr, nullptr, nullptr, nullptr, out);
    }
}

// Round 14
// 220.111 us; speedup vs baseline: 1.2861x; 1.0077x over previous
//
#include <hip/hip_runtime.h>
#include <hip/hip_bf16.h>

#define BB 2
#define TT 2048
#define CC 1024
#define HH 16
#define DH 64

typedef __attribute__((ext_vector_type(8))) short bf16x8;
typedef __attribute__((ext_vector_type(4))) float f32x4;
typedef __attribute__((ext_vector_type(16))) float f32x16;
using bf16 = __hip_bfloat16;
using u32 = unsigned int;

union cvt8u { bf16x8 v; bf16 b[8]; };

__device__ __forceinline__ bf16x8 load8(const bf16* p) {
    return *reinterpret_cast<const bf16x8*>(p);
}

__device__ __forceinline__ bf16x8 cvt8f(const float* p) {
    const float4 a = *reinterpret_cast<const float4*>(p);
    const float4 c = *reinterpret_cast<const float4*>(p + 4);
    cvt8u u;
    u.b[0] = __float2bfloat16(a.x); u.b[1] = __float2bfloat16(a.y);
    u.b[2] = __float2bfloat16(a.z); u.b[3] = __float2bfloat16(a.w);
    u.b[4] = __float2bfloat16(c.x); u.b[5] = __float2bfloat16(c.y);
    u.b[6] = __float2bfloat16(c.z); u.b[7] = __float2bfloat16(c.w);
    return u.v;
}

__device__ __forceinline__ f32x4 mfma16(bf16x8 a, bf16x8 b, f32x4 c) {
    return __builtin_amdgcn_mfma_f32_16x16x32_bf16(a, b, c, 0, 0, 0);
}

__device__ __forceinline__ f32x16 mfma32(bf16x8 a, bf16x8 b, f32x16 c) {
    return __builtin_amdgcn_mfma_f32_32x32x16_bf16(a, b, c, 0, 0, 0);
}

// pack two floats into one u32 of 2 bf16
__device__ __forceinline__ u32 pk2(float lo, float hi) {
    union { bf16 b; unsigned short u; } a, c;
    a.b = __float2bfloat16(lo);
    c.b = __float2bfloat16(hi);
    return (u32)a.u | ((u32)c.u << 16);
}

// async global->LDS, 16 B per lane (gemm3 staging). guide §5, m97/m104.
__device__ __forceinline__ void gload_lds16(const bf16* g, bf16* l) {
    __builtin_amdgcn_global_load_lds(
        (const __attribute__((address_space(1))) void*)g,
        (__attribute__((address_space(3))) void*)l, 16, 0, 0);
}

// Q pre-scale: 1/sqrt(64) * log2(e) -> attention uses exp2 directly.
#define QSCALE (0.125f * 1.44269504088896f)

// V^T SKEWED LAYOUT: element (d, t) stored at d*TT + ((t + d*64) & (TT-1)).

// ---------------- fp32 -> bf16 staging kernels ------------------------------
__global__ __launch_bounds__(256) void cvt_x(const float* __restrict__ in,
                                             bf16* __restrict__ out) {
    const int i = blockIdx.x * 256 + threadIdx.x;  // 524288 groups of 8
    *(reinterpret_cast<bf16x8*>(out) + i) = cvt8f(in + (size_t)i * 8);
}

__global__ __launch_bounds__(256) void cvt4_w(const float* __restrict__ w0,
                                              const float* __restrict__ w1,
                                              const float* __restrict__ w2,
                                              const float* __restrict__ w3,
                                              bf16* __restrict__ out) {
    const float* in = (blockIdx.y == 0) ? w0 : (blockIdx.y == 1) ? w1
                    : (blockIdx.y == 2) ? w2 : w3;
    const int i = blockIdx.x * 256 + threadIdx.x;  // 131072 groups of 8 per matrix
    bf16* o = out + (size_t)blockIdx.y * CC * CC;
    *(reinterpret_cast<bf16x8*>(o) + i) = cvt8f(in + (size_t)i * 8);
}

// ---------------- LDS-staged GEMM (m97 structure) ---------------------------
// (unchanged from round 5 — proven. MODE-0 Vt epilogue skewed.)
template <int MODE>
__global__ __launch_bounds__(256) void gemm3(const bf16* __restrict__ A,
                                             const bf16* __restrict__ B,
                                             bf16* __restrict__ oq,
                                             bf16* __restrict__ ok,
                                             bf16* __restrict__ ov,
                                             float* __restrict__ outf) {
    __shared__ __align__(16) bf16 As[128 * 32];  // 8 KB, [row][k] row-major
    __shared__ __align__(16) bf16 Bs[128 * 32];  // 8 KB
    const int lane = threadIdx.x & 63;
    const int wv = threadIdx.x >> 6;
    const int l15 = lane & 15;
    const int g = lane >> 4;
    const int m0 = blockIdx.x * 128;
    const int n0 = blockIdx.y * 128;

    const int srow = wv * 16 + (lane >> 2);
    const int skg = (lane & 3) * 8;
    const bf16* gA0 = A + (size_t)(m0 + srow) * CC + skg;
    const bf16* gA1 = A + (size_t)(m0 + 64 + srow) * CC + skg;
    const bf16* gB0 = B + (size_t)(n0 + srow) * CC + skg;
    const bf16* gB1 = B + (size_t)(n0 + 64 + srow) * CC + skg;
    bf16* lA0 = As + wv * 512;          // wave-uniform LDS bases
    bf16* lA1 = As + 2048 + wv * 512;
    bf16* lB0 = Bs + wv * 512;
    bf16* lB1 = Bs + 2048 + wv * 512;

    const int mw = (wv >> 1) * 64;  // wave's 64x64 sub-tile
    const int nw = (wv & 1) * 64;

    f32x4 acc[4][4] = {};

    for (int kk = 0; kk < CC; kk += 32) {
        __syncthreads();  // previous tile's ds_reads done before overwrite
        gload_lds16(gA0 + kk, lA0);
        gload_lds16(gA1 + kk, lA1);
        gload_lds16(gB0 + kk, lB0);
        gload_lds16(gB1 + kk, lB1);
        __syncthreads();  // vmcnt(0) drained before s_barrier -> tile ready

        bf16x8 af[4], wf[4];
#pragma unroll
        for (int mi = 0; mi < 4; mi++)
            af[mi] = load8(As + (mw + mi * 16 + l15) * 32 + g * 8);
#pragma unroll
        for (int ni = 0; ni < 4; ni++)
            wf[ni] = load8(Bs + (nw + ni * 16 + l15) * 32 + g * 8);
#pragma unroll
        for (int mi = 0; mi < 4; mi++)
#pragma unroll
            for (int ni = 0; ni < 4; ni++)
                acc[mi][ni] = mfma16(af[mi], wf[ni], acc[mi][ni]);
    }

#pragma unroll
    for (int mi = 0; mi < 4; mi++) {
#pragma unroll
        for (int ni = 0; ni < 4; ni++) {
            const int n = n0 + nw + ni * 16 + l15;  // C/D: col = lane&15
#pragma unroll
            for (int r = 0; r < 4; r++) {
                const int m = m0 + mw + mi * 16 + g * 4 + r;  // row=(lane>>4)*4+reg
                const float v = acc[mi][ni][r];
                if (MODE == 1) {
                    outf[(size_t)m * CC + n] = v;  // d_out is FLOAT32
                } else {
                    const int b = m >> 11, t = m & (TT - 1);
                    const int mat = n >> 10, nn = n & 1023;
                    const int h = nn >> 6, d = nn & 63;
                    if (mat == 0) {
                        oq[((size_t)((b * HH + h) * TT + t) << 6) + d] = __float2bfloat16(v * QSCALE);
                    } else if (mat == 1) {
                        ok[((size_t)((b * HH + h) * TT + t) << 6) + d] = __float2bfloat16(v);
                    } else {
                        // skewed V^T store (see layout comment above)
                        ov[(size_t)((b * HH + h) * DH + d) * TT + ((t + (d << 6)) & (TT - 1))] = __float2bfloat16(v);
                    }
                }
            }
        }
    }
}

// ---------------- register-direct GEMM (fallback, fp32 weights) -------------
template <int MODE>
__global__ __launch_bounds__(256) void gemm2(const bf16* __restrict__ A,
                                             const float* __restrict__ W0,
                                             const float* __restrict__ W1,
                                             const float* __restrict__ W2,
                                             bf16* __restrict__ oq,
                                             bf16* __restrict__ ok,
                                             bf16* __restrict__ ov,
                                             float* __restrict__ outf) {
    const int lane = threadIdx.x & 63;
    const int wv = threadIdx.x >> 6;
    const int l15 = lane & 15;
    const int g = lane >> 4;
    const int mw = blockIdx.x * 128 + (wv >> 1) * 64;
    const int nw = blockIdx.y * 128 + (wv & 1) * 64;

    f32x4 acc[4][4] = {};

    const bf16* ap[4];
#pragma unroll
    for (int mi = 0; mi < 4; mi++)
        ap[mi] = A + (size_t)(mw + mi * 16 + l15) * CC + g * 8;

    const float* wfp[4];
#pragma unroll
    for (int ni = 0; ni < 4; ni++) {
        const int nt = nw + ni * 16;
        const float* base = (MODE == 1) ? W0
                          : (nt < 1024) ? W0 : (nt < 2048) ? W1 : W2;
        wfp[ni] = base + (size_t)((nt & 1023) + l15) * CC + g * 8;
    }

#pragma unroll 2
    for (int kk = 0; kk < CC; kk += 32) {
        bf16x8 af[4], wf[4];
#pragma unroll
        for (int mi = 0; mi < 4; mi++) af[mi] = load8(ap[mi] + kk);
#pragma unroll
        for (int ni = 0; ni < 4; ni++) wf[ni] = cvt8f(wfp[ni] + kk);
#pragma unroll
        for (int mi = 0; mi < 4; mi++)
#pragma unroll
            for (int ni = 0; ni < 4; ni++)
                acc[mi][ni] = mfma16(af[mi], wf[ni], acc[mi][ni]);
    }

#pragma unroll
    for (int mi = 0; mi < 4; mi++) {
#pragma unroll
        for (int ni = 0; ni < 4; ni++) {
            const int n = nw + ni * 16 + l15;
#pragma unroll
            for (int r = 0; r < 4; r++) {
                const int m = mw + mi * 16 + g * 4 + r;
                const float v = acc[mi][ni][r];
                if (MODE == 1) {
                    outf[(size_t)m * CC + n] = v;
                } else {
                    const int b = m >> 11, t = m & (TT - 1);
                    const int mat = n >> 10, nn = n & 1023;
                    const int h = nn >> 6, d = nn & 63;
                    if (mat == 0) {
                        oq[((size_t)((b * HH + h) * TT + t) << 6) + d] = __float2bfloat16(v * QSCALE);
                    } else if (mat == 1) {
                        ok[((size_t)((b * HH + h) * TT + t) << 6) + d] = __float2bfloat16(v);
                    } else {
                        ov[(size_t)((b * HH + h) * DH + d) * TT + ((t + (d << 6)) & (TT - 1))] = __float2bfloat16(v);
                    }
                }
            }
        }
    }
}

// ---------------- MFMA flash attention v15 ----------------------------------
// v14 (32x32 swapped-QK^T + in-register softmax + depth-1 K/V prefetch) cut
// attn to 83us but the grid supplies only 4096 waves (2048 blk x 2) against
// a residency budget of 2-3x more at VGPR=76 / LDS=8.7KB — occupancy 22%,
// exposed L2 latency still dominates (~920 cyc wall vs ~250 issue). v15 =
// v14 with SPLIT-K x4: 4 waves per block stride key-blocks by kb%4, tripling
// publisher partials in the combine (LDS 24.7KB, ~6 blk/CU). 8192 waves = 2x
// latency-hiding TLP. Max-free softmax keeps partials exactly additive;
// zero-iteration waves publish zeros (correct). All else verbatim from v14.
__global__ __launch_bounds__(256, 2) void attn_v15(const bf16* __restrict__ Q,
                                                   const bf16* __restrict__ K,
                                                   const bf16* __restrict__ Vt,
                                                   bf16* __restrict__ out) {
    __shared__ __align__(64) float o_cmb[3][2][64][16];  // 24 KB
    __shared__ float l_cmb[3][32];                       // 384 B

    const int lane = threadIdx.x & 63;
    const int wv = threadIdx.x >> 6;   // 0..3 = split-K quarter
    const int l31 = lane & 31;
    const int hh = lane >> 5;          // 0..1 = lane half

    // bid -> (bh, c): XCD grouping + longest-first. Bijective on [0,2048).
    const int bid = blockIdx.x;
    const int xcd = bid & 7;
    const int idx = bid >> 3;            // 0..255
    const int bh = xcd * 4 + (idx >> 6); // 0..31
    const int c = 63 - (idx & 63);       // 0..63, longest first
    const int qb = c * 32;               // q rows [qb, qb+32)

    const bf16* Qh = Q + (size_t)bh * TT * DH;
    const bf16* Kh = K + (size_t)bh * TT * DH;
    const bf16* Vh = Vt + (size_t)bh * DH * TT;

    // Q fragments (B-operand of swapped QK): col=q=l31, k=d=hh*8+i, 4 chunks
    bf16x8 qf[4];
#pragma unroll
    for (int dc = 0; dc < 4; dc++)
        qf[dc] = load8(Qh + (size_t)(qb + l31) * DH + dc * 16 + hh * 8);

    f32x16 o0 = {}, o1 = {};   // O accum: [d=l31] and [d=32+l31]
    float l_part = 0.0f;

    const int qlane = qb + l31;
    const int d0 = l31, d1 = 32 + l31;
    const int s0 = d0 << 6, s1 = d1 << 6;

    // ---- initial K/V fragments for kb = wv (rows <= 127 always exist, so
    // waves that run zero iterations still load safely) -------------------
    bf16x8 kf[4], vf00, vf01, vf10, vf11;
    {
        const int k0 = wv * 32;
#pragma unroll
        for (int dc = 0; dc < 4; dc++)
            kf[dc] = load8(Kh + (size_t)(k0 + l31) * DH + dc * 16 + hh * 8);
        vf00 = load8(Vh + (size_t)d0 * TT + ((k0 + hh * 8 + s0) & (TT - 1)));
        vf01 = load8(Vh + (size_t)d0 * TT + ((k0 + 16 + hh * 8 + s0) & (TT - 1)));
        vf10 = load8(Vh + (size_t)d1 * TT + ((k0 + hh * 8 + s1) & (TT - 1)));
        vf11 = load8(Vh + (size_t)d1 * TT + ((k0 + 16 + hh * 8 + s1) & (TT - 1)));
    }

    for (int kb = wv; kb <= c; kb += 4) {
        const int k0 = kb * 32;
        const bool more = (kb + 4 <= c);  // wave-uniform

        // ---- prefetch NEXT iteration's K/V (lands under this iter's work)
        bf16x8 kfn[4], vn00, vn01, vn10, vn11;
        if (more) {
            const int kn = k0 + 128;
#pragma unroll
            for (int dc = 0; dc < 4; dc++)
                kfn[dc] = load8(Kh + (size_t)(kn + l31) * DH + dc * 16 + hh * 8);
            vn00 = load8(Vh + (size_t)d0 * TT + ((kn + hh * 8 + s0) & (TT - 1)));
            vn01 = load8(Vh + (size_t)d0 * TT + ((kn + 16 + hh * 8 + s0) & (TT - 1)));
            vn10 = load8(Vh + (size_t)d1 * TT + ((kn + hh * 8 + s1) & (TT - 1)));
            vn11 = load8(Vh + (size_t)d1 * TT + ((kn + 16 + hh * 8 + s1) & (TT - 1)));
        }

        // ---- S^T = K . Q^T over D=64 (4 mfma, one accumulator) -----------
        f32x16 S = {};
#pragma unroll
        for (int dc = 0; dc < 4; dc++) S = mfma32(kf[dc], qf[dc], S);

        // ---- causal mask (diagonal block only; key index = c_r + 4*hh) ---
        if (kb == c) {
#pragma unroll
            for (int r = 0; r < 16; r++) {
                const int c_r = (r & 3) + 8 * (r >> 2);
                if (k0 + c_r + 4 * hh > qlane) S[r] = -1e30f;
            }
        }

        // ---- exp2 (Q pre-scaled by log2e) + lane-local row-sum -----------
        float e[16];
#pragma unroll
        for (int r = 0; r < 16; r++) {
            e[r] = exp2f(S[r]);
            l_part += e[r];
        }

        // ---- pack P to bf16 pairs; half-exchange; build PV A-frags -------
        u32 w0 = pk2(e[0], e[1]),   w1 = pk2(e[2], e[3]);
        u32 w2 = pk2(e[4], e[5]),   w3 = pk2(e[6], e[7]);
        u32 w4 = pk2(e[8], e[9]),   w5 = pk2(e[10], e[11]);
        u32 w6 = pk2(e[12], e[13]), w7 = pk2(e[14], e[15]);
        const u32 x0 = __shfl_xor(w0, 32), x1 = __shfl_xor(w1, 32);
        const u32 x2 = __shfl_xor(w2, 32), x3 = __shfl_xor(w3, 32);
        const u32 x4 = __shfl_xor(w4, 32), x5 = __shfl_xor(w5, 32);
        const u32 x6 = __shfl_xor(w6, 32), x7 = __shfl_xor(w7, 32);

        union { u32 u[4]; bf16x8 v; } a1, a2;
        a1.u[0] = hh ? x2 : w0;  a1.u[1] = hh ? x3 : w1;
        a1.u[2] = hh ? w2 : x0;  a1.u[3] = hh ? w3 : x1;
        a2.u[0] = hh ? x6 : w4;  a2.u[1] = hh ? x7 : w5;
        a2.u[2] = hh ? w6 : x4;  a2.u[3] = hh ? w7 : x5;

        // ---- PV: O[q][d] += P[q][key16] . V[key16][d32]  (4 mfma) --------
        o0 = mfma32(a1.v, vf00, o0);
        o0 = mfma32(a2.v, vf01, o0);
        o1 = mfma32(a1.v, vf10, o1);
        o1 = mfma32(a2.v, vf11, o1);

        // ---- rotate double buffers ---------------------------------------
        if (more) {
#pragma unroll
            for (int dc = 0; dc < 4; dc++) kf[dc] = kfn[dc];
            vf00 = vn00; vf01 = vn01; vf10 = vn10; vf11 = vn11;
        }
    }

    // Fold the two lane-halves of the row sum.
    l_part += __shfl_xor(l_part, 32);

    // ---- split-K combine: waves 1..3 publish; wave 0 merges --------------
    if (wv > 0) {
        *reinterpret_cast<f32x16*>(&o_cmb[wv - 1][0][lane][0]) = o0;
        *reinterpret_cast<f32x16*>(&o_cmb[wv - 1][1][lane][0]) = o1;
        if (lane < 32) l_cmb[wv - 1][lane] = l_part;
    }
    __syncthreads();
    if (wv > 0) return;

#pragma unroll
    for (int w = 0; w < 3; w++) {
        o0 += *reinterpret_cast<const f32x16*>(&o_cmb[w][0][lane][0]);
        o1 += *reinterpret_cast<const f32x16*>(&o_cmb[w][1][lane][0]);
        l_part += l_cmb[w][l31];
    }
    const float linv = 1.0f / l_part;

    const int b = bh >> 4, h = bh & 15;
#pragma unroll
    for (int r = 0; r < 16; r++) {
        const int qrow = (r & 3) + 8 * (r >> 2) + 4 * hh;   // C/D row -> q
        const float inv = __shfl(linv, qrow);               // lane qrow holds it
        const int t = qb + qrow;
        bf16* op = out + (size_t)(b * TT + t) * CC + h * DH;
        op[l31] = __float2bfloat16(o0[r] * inv);
        op[32 + l31] = __float2bfloat16(o1[r] * inv);
    }
}

extern "C" void kernel_launch(void* const* d_in, const int* in_sizes, int n_in,
                              void* d_out, int out_size, void* d_ws, size_t ws_size,
                              hipStream_t stream) {
    const float* x  = (const float*)d_in[0];
    const float* Wq = (const float*)d_in[1];
    const float* Wk = (const float*)d_in[2];
    const float* Wv = (const float*)d_in[3];
    const float* Wo = (const float*)d_in[4];
    float* out = (float*)d_out;  // reference output dtype is float32

    const size_t per = (size_t)BB * HH * TT * DH;  // 4,194,304 elems
    bf16* Qws  = (bf16*)d_ws;       // 8 MB
    bf16* Kws  = Qws + per;         // 8 MB
    bf16* Vtws = Kws + per;         // 8 MB (skewed layout)
    bf16* xbf  = Vtws + per;        // 8 MB — attn output aliases (x dead after QKV)
    bf16* attn = xbf;
    bf16* Wball = attn + per;       // 8 MB (4 bf16 weight mats) — needs ws >= 40 MB
    const bool full = ws_size >= 5 * per * sizeof(bf16);

    const dim3 blk(256);
    cvt_x<<<dim3(2048), blk, 0, stream>>>(x, xbf);

    if (full) {
        cvt4_w<<<dim3(512, 4), blk, 0, stream>>>(Wq, Wk, Wv, Wo, Wball);
        gemm3<0><<<dim3(32, 24), blk, 0, stream>>>(
            xbf, Wball, Qws, Kws, Vtws, nullptr);
    } else {
        gemm2<0><<<dim3(32, 24), blk, 0, stream>>>(
            xbf, Wq, Wk, Wv, Qws, Kws, Vtws, nullptr);
    }

    attn_v15<<<dim3(2048), dim3(256), 0, stream>>>(Qws, Kws, Vtws, attn);

    if (full) {
        gemm3<1><<<dim3(32, 8), blk, 0, stream>>>(
            attn, Wball + (size_t)3 * CC * CC, nullptr, nullptr, nullptr, out);
    } else {
        gemm2<1><<<dim3(32, 8), blk, 0, stream>>>(
            attn, Wo, nullptr, nullptr, nullptr, nullptr, nullptr, out);
    }
}

// Round 15
// 214.347 us; speedup vs baseline: 1.3207x; 1.0269x over previous
//
#include <hip/hip_runtime.h>
#include <hip/hip_bf16.h>

#define BB 2
#define TT 2048
#define CC 1024
#define HH 16
#define DH 64

typedef __attribute__((ext_vector_type(8))) short bf16x8;
typedef __attribute__((ext_vector_type(4))) float f32x4;
typedef __attribute__((ext_vector_type(16))) float f32x16;
using bf16 = __hip_bfloat16;
using u32 = unsigned int;

union cvt8u { bf16x8 v; bf16 b[8]; };

__device__ __forceinline__ bf16x8 load8(const bf16* p) {
    return *reinterpret_cast<const bf16x8*>(p);
}

__device__ __forceinline__ bf16x8 cvt8f(const float* p) {
    const float4 a = *reinterpret_cast<const float4*>(p);
    const float4 c = *reinterpret_cast<const float4*>(p + 4);
    cvt8u u;
    u.b[0] = __float2bfloat16(a.x); u.b[1] = __float2bfloat16(a.y);
    u.b[2] = __float2bfloat16(a.z); u.b[3] = __float2bfloat16(a.w);
    u.b[4] = __float2bfloat16(c.x); u.b[5] = __float2bfloat16(c.y);
    u.b[6] = __float2bfloat16(c.z); u.b[7] = __float2bfloat16(c.w);
    return u.v;
}

__device__ __forceinline__ f32x4 mfma16(bf16x8 a, bf16x8 b, f32x4 c) {
    return __builtin_amdgcn_mfma_f32_16x16x32_bf16(a, b, c, 0, 0, 0);
}

__device__ __forceinline__ f32x16 mfma32(bf16x8 a, bf16x8 b, f32x16 c) {
    return __builtin_amdgcn_mfma_f32_32x32x16_bf16(a, b, c, 0, 0, 0);
}

// pack two floats into one u32 of 2 bf16 (compiler pattern-matches to cvt_pk;
// per guide m240, do NOT hand-write the asm)
__device__ __forceinline__ u32 pk2(float lo, float hi) {
    union { bf16 b; unsigned short u; } a, c;
    a.b = __float2bfloat16(lo);
    c.b = __float2bfloat16(hi);
    return (u32)a.u | ((u32)c.u << 16);
}

// async global->LDS, 16 B per lane (gemm3 staging). guide §5, m97/m104.
__device__ __forceinline__ void gload_lds16(const bf16* g, bf16* l) {
    __builtin_amdgcn_global_load_lds(
        (const __attribute__((address_space(1))) void*)g,
        (__attribute__((address_space(3))) void*)l, 16, 0, 0);
}

// Q pre-scale: 1/sqrt(64) * log2(e) -> attention uses exp2 directly.
#define QSCALE (0.125f * 1.44269504088896f)

// V^T SKEWED LAYOUT: element (d, t) stored at d*TT + ((t + d*64) & (TT-1)).

// ---------------- fp32 -> bf16 staging kernels ------------------------------
__global__ __launch_bounds__(256) void cvt_x(const float* __restrict__ in,
                                             bf16* __restrict__ out) {
    const int i = blockIdx.x * 256 + threadIdx.x;  // 524288 groups of 8
    *(reinterpret_cast<bf16x8*>(out) + i) = cvt8f(in + (size_t)i * 8);
}

__global__ __launch_bounds__(256) void cvt4_w(const float* __restrict__ w0,
                                              const float* __restrict__ w1,
                                              const float* __restrict__ w2,
                                              const float* __restrict__ w3,
                                              bf16* __restrict__ out) {
    const float* in = (blockIdx.y == 0) ? w0 : (blockIdx.y == 1) ? w1
                    : (blockIdx.y == 2) ? w2 : w3;
    const int i = blockIdx.x * 256 + threadIdx.x;  // 131072 groups of 8 per matrix
    bf16* o = out + (size_t)blockIdx.y * CC * CC;
    *(reinterpret_cast<bf16x8*>(o) + i) = cvt8f(in + (size_t)i * 8);
}

// ---------------- LDS-staged GEMM (m97 structure) ---------------------------
// (unchanged from round 5 — proven. MODE-0 Vt epilogue skewed.)
template <int MODE>
__global__ __launch_bounds__(256) void gemm3(const bf16* __restrict__ A,
                                             const bf16* __restrict__ B,
                                             bf16* __restrict__ oq,
                                             bf16* __restrict__ ok,
                                             bf16* __restrict__ ov,
                                             float* __restrict__ outf) {
    __shared__ __align__(16) bf16 As[128 * 32];  // 8 KB, [row][k] row-major
    __shared__ __align__(16) bf16 Bs[128 * 32];  // 8 KB
    const int lane = threadIdx.x & 63;
    const int wv = threadIdx.x >> 6;
    const int l15 = lane & 15;
    const int g = lane >> 4;
    const int m0 = blockIdx.x * 128;
    const int n0 = blockIdx.y * 128;

    const int srow = wv * 16 + (lane >> 2);
    const int skg = (lane & 3) * 8;
    const bf16* gA0 = A + (size_t)(m0 + srow) * CC + skg;
    const bf16* gA1 = A + (size_t)(m0 + 64 + srow) * CC + skg;
    const bf16* gB0 = B + (size_t)(n0 + srow) * CC + skg;
    const bf16* gB1 = B + (size_t)(n0 + 64 + srow) * CC + skg;
    bf16* lA0 = As + wv * 512;          // wave-uniform LDS bases
    bf16* lA1 = As + 2048 + wv * 512;
    bf16* lB0 = Bs + wv * 512;
    bf16* lB1 = Bs + 2048 + wv * 512;

    const int mw = (wv >> 1) * 64;  // wave's 64x64 sub-tile
    const int nw = (wv & 1) * 64;

    f32x4 acc[4][4] = {};

    for (int kk = 0; kk < CC; kk += 32) {
        __syncthreads();  // previous tile's ds_reads done before overwrite
        gload_lds16(gA0 + kk, lA0);
        gload_lds16(gA1 + kk, lA1);
        gload_lds16(gB0 + kk, lB0);
        gload_lds16(gB1 + kk, lB1);
        __syncthreads();  // vmcnt(0) drained before s_barrier -> tile ready

        bf16x8 af[4], wf[4];
#pragma unroll
        for (int mi = 0; mi < 4; mi++)
            af[mi] = load8(As + (mw + mi * 16 + l15) * 32 + g * 8);
#pragma unroll
        for (int ni = 0; ni < 4; ni++)
            wf[ni] = load8(Bs + (nw + ni * 16 + l15) * 32 + g * 8);
#pragma unroll
        for (int mi = 0; mi < 4; mi++)
#pragma unroll
            for (int ni = 0; ni < 4; ni++)
                acc[mi][ni] = mfma16(af[mi], wf[ni], acc[mi][ni]);
    }

#pragma unroll
    for (int mi = 0; mi < 4; mi++) {
#pragma unroll
        for (int ni = 0; ni < 4; ni++) {
            const int n = n0 + nw + ni * 16 + l15;  // C/D: col = lane&15
#pragma unroll
            for (int r = 0; r < 4; r++) {
                const int m = m0 + mw + mi * 16 + g * 4 + r;  // row=(lane>>4)*4+reg
                const float v = acc[mi][ni][r];
                if (MODE == 1) {
                    outf[(size_t)m * CC + n] = v;  // d_out is FLOAT32
                } else {
                    const int b = m >> 11, t = m & (TT - 1);
                    const int mat = n >> 10, nn = n & 1023;
                    const int h = nn >> 6, d = nn & 63;
                    if (mat == 0) {
                        oq[((size_t)((b * HH + h) * TT + t) << 6) + d] = __float2bfloat16(v * QSCALE);
                    } else if (mat == 1) {
                        ok[((size_t)((b * HH + h) * TT + t) << 6) + d] = __float2bfloat16(v);
                    } else {
                        // skewed V^T store (see layout comment above)
                        ov[(size_t)((b * HH + h) * DH + d) * TT + ((t + (d << 6)) & (TT - 1))] = __float2bfloat16(v);
                    }
                }
            }
        }
    }
}

// ---------------- register-direct GEMM (fallback, fp32 weights) -------------
template <int MODE>
__global__ __launch_bounds__(256) void gemm2(const bf16* __restrict__ A,
                                             const float* __restrict__ W0,
                                             const float* __restrict__ W1,
                                             const float* __restrict__ W2,
                                             bf16* __restrict__ oq,
                                             bf16* __restrict__ ok,
                                             bf16* __restrict__ ov,
                                             float* __restrict__ outf) {
    const int lane = threadIdx.x & 63;
    const int wv = threadIdx.x >> 6;
    const int l15 = lane & 15;
    const int g = lane >> 4;
    const int mw = blockIdx.x * 128 + (wv >> 1) * 64;
    const int nw = blockIdx.y * 128 + (wv & 1) * 64;

    f32x4 acc[4][4] = {};

    const bf16* ap[4];
#pragma unroll
    for (int mi = 0; mi < 4; mi++)
        ap[mi] = A + (size_t)(mw + mi * 16 + l15) * CC + g * 8;

    const float* wfp[4];
#pragma unroll
    for (int ni = 0; ni < 4; ni++) {
        const int nt = nw + ni * 16;
        const float* base = (MODE == 1) ? W0
                          : (nt < 1024) ? W0 : (nt < 2048) ? W1 : W2;
        wfp[ni] = base + (size_t)((nt & 1023) + l15) * CC + g * 8;
    }

#pragma unroll 2
    for (int kk = 0; kk < CC; kk += 32) {
        bf16x8 af[4], wf[4];
#pragma unroll
        for (int mi = 0; mi < 4; mi++) af[mi] = load8(ap[mi] + kk);
#pragma unroll
        for (int ni = 0; ni < 4; ni++) wf[ni] = cvt8f(wfp[ni] + kk);
#pragma unroll
        for (int mi = 0; mi < 4; mi++)
#pragma unroll
            for (int ni = 0; ni < 4; ni++)
                acc[mi][ni] = mfma16(af[mi], wf[ni], acc[mi][ni]);
    }

#pragma unroll
    for (int mi = 0; mi < 4; mi++) {
#pragma unroll
        for (int ni = 0; ni < 4; ni++) {
            const int n = nw + ni * 16 + l15;
#pragma unroll
            for (int r = 0; r < 4; r++) {
                const int m = mw + mi * 16 + g * 4 + r;
                const float v = acc[mi][ni][r];
                if (MODE == 1) {
                    outf[(size_t)m * CC + n] = v;
                } else {
                    const int b = m >> 11, t = m & (TT - 1);
                    const int mat = n >> 10, nn = n & 1023;
                    const int h = nn >> 6, d = nn & 63;
                    if (mat == 0) {
                        oq[((size_t)((b * HH + h) * TT + t) << 6) + d] = __float2bfloat16(v * QSCALE);
                    } else if (mat == 1) {
                        ok[((size_t)((b * HH + h) * TT + t) << 6) + d] = __float2bfloat16(v);
                    } else {
                        ov[(size_t)((b * HH + h) * DH + d) * TT + ((t + (d << 6)) & (TT - 1))] = __float2bfloat16(v);
                    }
                }
            }
        }
    }
}

// ---------------- MFMA flash attention v16 ----------------------------------
// v14 (32x32 swapped-QK^T + in-reg softmax + depth-1 prefetch) = 83.3us.
// v15 (split-K x4, 2x waves) = 86us -> TLP conclusively NOT the lever (3rd
// confirmation). Remaining per-iteration cost: softmax/pack VALU (scales
// with S-elements, irreducible here) + fixed overhead (loads, loop control,
// addresses). v16 attacks the fixed part: TWO q-tiles per wave {2c, 2c+1}
// share ONE set of K/V fragments and one loop -> iterations halve
// (66,560 -> 33,792). Register cost is only +16 qf +32 acc (start was 76;
// fits (128,2)'s 256 cap, no spill expected — WRITE_SIZE is the detector).
// Plus T5: s_setprio(1) around MFMA clusters (verified +4-7% attn, m191).
// Tile A (rows [64c,64c+32)) is inactive only on the final k-block of odd
// parity (kb == 2c+1): <=3% masked waste.
__global__ __launch_bounds__(128, 2) void attn_v16(const bf16* __restrict__ Q,
                                                   const bf16* __restrict__ K,
                                                   const bf16* __restrict__ Vt,
                                                   bf16* __restrict__ out) {
    __shared__ __align__(64) float o_cmb[2][2][64][16];  // 16 KB [tile][dhalf]
    __shared__ float l_cmb[2][32];                       // 256 B

    const int lane = threadIdx.x & 63;
    const int wv = threadIdx.x >> 6;   // 0..1 = split-K half
    const int l31 = lane & 31;
    const int hh = lane >> 5;          // 0..1 = lane half

    // bid -> (bh, c): XCD grouping + longest-first. Bijective on [0,1024).
    const int bid = blockIdx.x;
    const int xcd = bid & 7;
    const int idx = bid >> 3;            // 0..127
    const int bh = xcd * 4 + (idx >> 5); // 0..31
    const int c = 31 - (idx & 31);       // 0..31, longest first
    const int qbA = c * 64;              // tile A rows [qbA, qbA+32)
    const int qbB = c * 64 + 32;         // tile B rows [qbB, qbB+32)
    const int kbmax = 2 * c + 1;         // last 32-key block (tile B diagonal)

    const bf16* Qh = Q + (size_t)bh * TT * DH;
    const bf16* Kh = K + (size_t)bh * TT * DH;
    const bf16* Vh = Vt + (size_t)bh * DH * TT;

    // Q fragments (B-operand of swapped QK): col=q=l31, k=d=hh*8+i
    bf16x8 qfA[4], qfB[4];
#pragma unroll
    for (int dc = 0; dc < 4; dc++) {
        qfA[dc] = load8(Qh + (size_t)(qbA + l31) * DH + dc * 16 + hh * 8);
        qfB[dc] = load8(Qh + (size_t)(qbB + l31) * DH + dc * 16 + hh * 8);
    }

    f32x16 oA0 = {}, oA1 = {}, oB0 = {}, oB1 = {};
    float lA = 0.0f, lB = 0.0f;

    const int qlaneA = qbA + l31;
    const int qlaneB = qbB + l31;
    const int d0 = l31, d1 = 32 + l31;
    const int s0 = d0 << 6, s1 = d1 << 6;

    // ---- initial K/V fragments for kb = wv (kb <= kbmax always since
    // kbmax >= 1; rows < 2048 safe) ---------------------------------------
    bf16x8 kf[4], vf00, vf01, vf10, vf11;
    {
        const int k0 = wv * 32;
#pragma unroll
        for (int dc = 0; dc < 4; dc++)
            kf[dc] = load8(Kh + (size_t)(k0 + l31) * DH + dc * 16 + hh * 8);
        vf00 = load8(Vh + (size_t)d0 * TT + ((k0 + hh * 8 + s0) & (TT - 1)));
        vf01 = load8(Vh + (size_t)d0 * TT + ((k0 + 16 + hh * 8 + s0) & (TT - 1)));
        vf10 = load8(Vh + (size_t)d1 * TT + ((k0 + hh * 8 + s1) & (TT - 1)));
        vf11 = load8(Vh + (size_t)d1 * TT + ((k0 + 16 + hh * 8 + s1) & (TT - 1)));
    }

    for (int kb = wv; kb <= kbmax; kb += 2) {
        const int k0 = kb * 32;
        const bool more = (kb + 2 <= kbmax);   // wave-uniform
        const bool actA = (kb <= 2 * c);       // tile A inactive only on 2c+1

        // ---- prefetch NEXT iteration's K/V (lands under this iter's work)
        bf16x8 kfn[4], vn00, vn01, vn10, vn11;
        if (more) {
            const int kn = k0 + 64;
#pragma unroll
            for (int dc = 0; dc < 4; dc++)
                kfn[dc] = load8(Kh + (size_t)(kn + l31) * DH + dc * 16 + hh * 8);
            vn00 = load8(Vh + (size_t)d0 * TT + ((kn + hh * 8 + s0) & (TT - 1)));
            vn01 = load8(Vh + (size_t)d0 * TT + ((kn + 16 + hh * 8 + s0) & (TT - 1)));
            vn10 = load8(Vh + (size_t)d1 * TT + ((kn + hh * 8 + s1) & (TT - 1)));
            vn11 = load8(Vh + (size_t)d1 * TT + ((kn + 16 + hh * 8 + s1) & (TT - 1)));
        }

        // ---- S^T = K . Q^T for both tiles (K fragments shared) -----------
        f32x16 SA = {}, SB = {};
        __builtin_amdgcn_s_setprio(1);
        if (actA) {
#pragma unroll
            for (int dc = 0; dc < 4; dc++) SA = mfma32(kf[dc], qfA[dc], SA);
        }
#pragma unroll
        for (int dc = 0; dc < 4; dc++) SB = mfma32(kf[dc], qfB[dc], SB);
        __builtin_amdgcn_s_setprio(0);

        // ---- causal masks (wave-uniform block conditions) ----------------
        if (kb == 2 * c) {  // tile A diagonal
#pragma unroll
            for (int r = 0; r < 16; r++) {
                const int c_r = (r & 3) + 8 * (r >> 2);
                if (k0 + c_r + 4 * hh > qlaneA) SA[r] = -1e30f;
            }
        }
        if (kb == kbmax) {  // tile B diagonal
#pragma unroll
            for (int r = 0; r < 16; r++) {
                const int c_r = (r & 3) + 8 * (r >> 2);
                if (k0 + c_r + 4 * hh > qlaneB) SB[r] = -1e30f;
            }
        }

        // ---- tile A: exp2 -> pack -> half-exchange -> PV -----------------
        if (actA) {
            float e[16];
#pragma unroll
            for (int r = 0; r < 16; r++) {
                e[r] = exp2f(SA[r]);
                lA += e[r];
            }
            u32 w0 = pk2(e[0], e[1]),   w1 = pk2(e[2], e[3]);
            u32 w2 = pk2(e[4], e[5]),   w3 = pk2(e[6], e[7]);
            u32 w4 = pk2(e[8], e[9]),   w5 = pk2(e[10], e[11]);
            u32 w6 = pk2(e[12], e[13]), w7 = pk2(e[14], e[15]);
            const u32 x0 = __shfl_xor(w0, 32), x1 = __shfl_xor(w1, 32);
            const u32 x2 = __shfl_xor(w2, 32), x3 = __shfl_xor(w3, 32);
            const u32 x4 = __shfl_xor(w4, 32), x5 = __shfl_xor(w5, 32);
            const u32 x6 = __shfl_xor(w6, 32), x7 = __shfl_xor(w7, 32);
            union { u32 u[4]; bf16x8 v; } a1, a2;
            a1.u[0] = hh ? x2 : w0;  a1.u[1] = hh ? x3 : w1;
            a1.u[2] = hh ? w2 : x0;  a1.u[3] = hh ? w3 : x1;
            a2.u[0] = hh ? x6 : w4;  a2.u[1] = hh ? x7 : w5;
            a2.u[2] = hh ? w6 : x4;  a2.u[3] = hh ? w7 : x5;
            __builtin_amdgcn_s_setprio(1);
            oA0 = mfma32(a1.v, vf00, oA0);
            oA0 = mfma32(a2.v, vf01, oA0);
            oA1 = mfma32(a1.v, vf10, oA1);
            oA1 = mfma32(a2.v, vf11, oA1);
            __builtin_amdgcn_s_setprio(0);
        }

        // ---- tile B: exp2 -> pack -> half-exchange -> PV -----------------
        {
            float e[16];
#pragma unroll
            for (int r = 0; r < 16; r++) {
                e[r] = exp2f(SB[r]);
                lB += e[r];
            }
            u32 w0 = pk2(e[0], e[1]),   w1 = pk2(e[2], e[3]);
            u32 w2 = pk2(e[4], e[5]),   w3 = pk2(e[6], e[7]);
            u32 w4 = pk2(e[8], e[9]),   w5 = pk2(e[10], e[11]);
            u32 w6 = pk2(e[12], e[13]), w7 = pk2(e[14], e[15]);
            const u32 x0 = __shfl_xor(w0, 32), x1 = __shfl_xor(w1, 32);
            const u32 x2 = __shfl_xor(w2, 32), x3 = __shfl_xor(w3, 32);
            const u32 x4 = __shfl_xor(w4, 32), x5 = __shfl_xor(w5, 32);
            const u32 x6 = __shfl_xor(w6, 32), x7 = __shfl_xor(w7, 32);
            union { u32 u[4]; bf16x8 v; } a1, a2;
            a1.u[0] = hh ? x2 : w0;  a1.u[1] = hh ? x3 : w1;
            a1.u[2] = hh ? w2 : x0;  a1.u[3] = hh ? w3 : x1;
            a2.u[0] = hh ? x6 : w4;  a2.u[1] = hh ? x7 : w5;
            a2.u[2] = hh ? w6 : x4;  a2.u[3] = hh ? w7 : x5;
            __builtin_amdgcn_s_setprio(1);
            oB0 = mfma32(a1.v, vf00, oB0);
            oB0 = mfma32(a2.v, vf01, oB0);
            oB1 = mfma32(a1.v, vf10, oB1);
            oB1 = mfma32(a2.v, vf11, oB1);
            __builtin_amdgcn_s_setprio(0);
        }

        // ---- rotate double buffers ---------------------------------------
        if (more) {
#pragma unroll
            for (int dc = 0; dc < 4; dc++) kf[dc] = kfn[dc];
            vf00 = vn00; vf01 = vn01; vf10 = vn10; vf11 = vn11;
        }
    }

    // Fold the two lane-halves of the row sums.
    lA += __shfl_xor(lA, 32);
    lB += __shfl_xor(lB, 32);

    // ---- split-K combine: wave 1 publishes; wave 0 merges ----------------
    if (wv == 1) {
        *reinterpret_cast<f32x16*>(&o_cmb[0][0][lane][0]) = oA0;
        *reinterpret_cast<f32x16*>(&o_cmb[0][1][lane][0]) = oA1;
        *reinterpret_cast<f32x16*>(&o_cmb[1][0][lane][0]) = oB0;
        *reinterpret_cast<f32x16*>(&o_cmb[1][1][lane][0]) = oB1;
        if (lane < 32) {
            l_cmb[0][lane] = lA;
            l_cmb[1][lane] = lB;
        }
    }
    __syncthreads();
    if (wv == 1) return;

    oA0 += *reinterpret_cast<const f32x16*>(&o_cmb[0][0][lane][0]);
    oA1 += *reinterpret_cast<const f32x16*>(&o_cmb[0][1][lane][0]);
    oB0 += *reinterpret_cast<const f32x16*>(&o_cmb[1][0][lane][0]);
    oB1 += *reinterpret_cast<const f32x16*>(&o_cmb[1][1][lane][0]);
    const float linvA = 1.0f / (lA + l_cmb[0][l31]);
    const float linvB = 1.0f / (lB + l_cmb[1][l31]);

    const int b = bh >> 4, h = bh & 15;
#pragma unroll
    for (int r = 0; r < 16; r++) {
        const int qrow = (r & 3) + 8 * (r >> 2) + 4 * hh;   // C/D row -> q
        const float invA = __shfl(linvA, qrow);
        const float invB = __shfl(linvB, qrow);
        bf16* opA = out + (size_t)(b * TT + qbA + qrow) * CC + h * DH;
        bf16* opB = out + (size_t)(b * TT + qbB + qrow) * CC + h * DH;
        opA[l31] = __float2bfloat16(oA0[r] * invA);
        opA[32 + l31] = __float2bfloat16(oA1[r] * invA);
        opB[l31] = __float2bfloat16(oB0[r] * invB);
        opB[32 + l31] = __float2bfloat16(oB1[r] * invB);
    }
}

extern "C" void kernel_launch(void* const* d_in, const int* in_sizes, int n_in,
                              void* d_out, int out_size, void* d_ws, size_t ws_size,
                              hipStream_t stream) {
    const float* x  = (const float*)d_in[0];
    const float* Wq = (const float*)d_in[1];
    const float* Wk = (const float*)d_in[2];
    const float* Wv = (const float*)d_in[3];
    const float* Wo = (const float*)d_in[4];
    float* out = (float*)d_out;  // reference output dtype is float32

    const size_t per = (size_t)BB * HH * TT * DH;  // 4,194,304 elems
    bf16* Qws  = (bf16*)d_ws;       // 8 MB
    bf16* Kws  = Qws + per;         // 8 MB
    bf16* Vtws = Kws + per;         // 8 MB (skewed layout)
    bf16* xbf  = Vtws + per;        // 8 MB — attn output aliases (x dead after QKV)
    bf16* attn = xbf;
    bf16* Wball = attn + per;       // 8 MB (4 bf16 weight mats) — needs ws >= 40 MB
    const bool full = ws_size >= 5 * per * sizeof(bf16);

    const dim3 blk(256);
    cvt_x<<<dim3(2048), blk, 0, stream>>>(x, xbf);

    if (full) {
        cvt4_w<<<dim3(512, 4), blk, 0, stream>>>(Wq, Wk, Wv, Wo, Wball);
        gemm3<0><<<dim3(32, 24), blk, 0, stream>>>(
            xbf, Wball, Qws, Kws, Vtws, nullptr);
    } else {
        gemm2<0><<<dim3(32, 24), blk, 0, stream>>>(
            xbf, Wq, Wk, Wv, Qws, Kws, Vtws, nullptr);
    }

    attn_v16<<<dim3(1024), dim3(128), 0, stream>>>(Qws, Kws, Vtws, attn);

    if (full) {
        gemm3<1><<<dim3(32, 8), blk, 0, stream>>>(
            attn, Wball + (size_t)3 * CC * CC, nullptr, nullptr, nullptr, out);
    } else {
        gemm2<1><<<dim3(32, 8), blk, 0, stream>>>(
            attn, Wo, nullptr, nullptr, nullptr, nullptr, nullptr, out);
    }
}